// Round 5
// baseline (421.635 us; speedup 1.0000x reference)
//
#include <hip/hip_runtime.h>
#include <hip/hip_bf16.h>
#include <stdint.h>

// ---------------------------------------------------------------------------
// Block: LN -> [q,k,v,p] = h @ w_in^T -> key-smear -> causal attn w/ learned
// ALiBi -> o * silu(p) -> @ w_out^T -> LN.   B=2 L=2048 D=1024 H=16 Dh=128.
// Internal compute in bf16 MFMA.
// ---------------------------------------------------------------------------

typedef __bf16 bf16;
typedef bf16  bf16x8 __attribute__((ext_vector_type(8)));
typedef float f32x4  __attribute__((ext_vector_type(4)));

#define SEQ   2048
#define NBATC 2

__device__ __forceinline__ void gld_lds16(const bf16* g, bf16* l) {
  __builtin_amdgcn_global_load_lds((const __attribute__((address_space(1))) void*)g,
                                   (__attribute__((address_space(3))) void*)l, 16, 0, 0);
}

// ---------------- f32 -> bf16 convert (8 elems/thread) ----------------------
__global__ __launch_bounds__(256) void cvt_kernel(const float* __restrict__ in,
                                                  bf16* __restrict__ out, int n8) {
  int t = blockIdx.x * 256 + threadIdx.x;
  if (t >= n8) return;
  const float4* p = (const float4*)in + (size_t)t * 2;
  float4 a = p[0], b = p[1];
  bf16x8 o;
  o[0] = (bf16)a.x; o[1] = (bf16)a.y; o[2] = (bf16)a.z; o[3] = (bf16)a.w;
  o[4] = (bf16)b.x; o[5] = (bf16)b.y; o[6] = (bf16)b.z; o[7] = (bf16)b.w;
  *((bf16x8*)out + t) = o;
}

// ---------------- LayerNorm over rows of 1024 f32 ---------------------------
template<bool BF16OUT>
__global__ __launch_bounds__(256) void ln_kernel(const float* __restrict__ x,
    const float* __restrict__ gamma, const float* __restrict__ beta,
    void* __restrict__ out) {
  const int row = blockIdx.x;
  const int tid = threadIdx.x;
  float4 v = *(const float4*)(x + (size_t)row * 1024 + tid * 4);
  float s  = v.x + v.y + v.z + v.w;
  float ss = v.x * v.x + v.y * v.y + v.z * v.z + v.w * v.w;
#pragma unroll
  for (int m = 1; m < 64; m <<= 1) { s += __shfl_xor(s, m, 64); ss += __shfl_xor(ss, m, 64); }
  __shared__ float red[8];
  if ((tid & 63) == 0) { red[tid >> 6] = s; red[(tid >> 6) + 4] = ss; }
  __syncthreads();
  s  = red[0] + red[1] + red[2] + red[3];
  ss = red[4] + red[5] + red[6] + red[7];
  const float mu  = s * (1.f / 1024.f);
  const float inv = rsqrtf(ss * (1.f / 1024.f) - mu * mu + 1e-5f);
  float4 g  = *(const float4*)(gamma + tid * 4);
  float4 bb = *(const float4*)(beta  + tid * 4);
  float y0 = (v.x - mu) * inv * g.x + bb.x;
  float y1 = (v.y - mu) * inv * g.y + bb.y;
  float y2 = (v.z - mu) * inv * g.z + bb.z;
  float y3 = (v.w - mu) * inv * g.w + bb.w;
  if (BF16OUT) {
    bf16* o = (bf16*)out + (size_t)row * 1024 + tid * 4;
    o[0] = (bf16)y0; o[1] = (bf16)y1; o[2] = (bf16)y2; o[3] = (bf16)y3;
  } else {
    float* o = (float*)out + (size_t)row * 1024 + tid * 4;
    o[0] = y0; o[1] = y1; o[2] = y2; o[3] = y3;
  }
}

// ---------------- key smear -> ksm (plain [bh][i][d]) -----------------------
__global__ __launch_bounds__(256) void smear_kernel(const bf16* __restrict__ qkvp,
    const float* __restrict__ smf, bf16* __restrict__ ksm) {
  int t  = blockIdx.x * 256 + threadIdx.x;   // 2^20 vec8 groups
  int d8 = t & 15;
  int i  = (t >> 4) & 2047;
  int h  = (t >> 15) & 15;
  int b  = t >> 19;
  float sm = 1.f / (1.f + __expf(-smf[h]));
  const bf16* base = qkvp + (size_t)(b * SEQ + i) * 8192 + 2048 + h * 128 + d8 * 8;
  bf16x8 cur = *(const bf16x8*)base;
  bf16x8 prv = cur;
  if (i > 0) prv = *(const bf16x8*)(base - 8192);
  bf16x8 o;
#pragma unroll
  for (int e = 0; e < 8; e++) {
    float pv = (i > 0) ? (float)prv[e] : 0.f;
    o[e] = (bf16)((1.f - sm) * (float)cur[e] + sm * pv);
  }
  *(bf16x8*)(ksm + ((size_t)(b * 16 + h) * SEQ + i) * 128 + d8 * 8) = o;
}

// ---------------- V transpose: vt[bh][kt][d][i0..63] (plain) ----------------
__global__ __launch_bounds__(256) void vtrans_kernel(const bf16* __restrict__ qkvp,
                                                     bf16* __restrict__ vt) {
  __shared__ bf16 T[128][72];
  const int kt = blockIdx.x, bh = blockIdx.y;
  const int b = bh >> 4, h = bh & 15;
  const int t = threadIdx.x;
  {
    int i = t >> 2, d0 = (t & 3) * 32;
    const bf16* src = qkvp + (size_t)(b * SEQ + kt * 64 + i) * 8192 + 4096 + h * 128 + d0;
#pragma unroll
    for (int m = 0; m < 4; m++) {
      bf16x8 v8 = *(const bf16x8*)(src + m * 8);
#pragma unroll
      for (int e = 0; e < 8; e++) T[d0 + m * 8 + e][i] = v8[e];
    }
  }
  __syncthreads();
  {
    int d = t >> 1, i0 = (t & 1) * 32;
    bf16* dst = vt + (size_t)bh * (SEQ * 128) + (size_t)kt * 8192 + d * 64;
#pragma unroll
    for (int m = 0; m < 4; m++) {
      bf16x8 v8 = *(const bf16x8*)&T[d][i0 + m * 8];
      *(bf16x8*)(dst + i0 + m * 8) = v8;
    }
  }
}

// ---------------- GEMM: C[M][N] = A[M][K] * Bt[N][K]^T  (bf16 MFMA) ---------
// 1D grid; supertile-chunked XCD swizzle: XCD j (= wgid&7) owns a compact
// SXxSY region of the (N/128)x(M/128) tile grid -> A/B panels stay in its L2.
template<typename OutT>
__global__ __launch_bounds__(256) void gemm_bt(const bf16* __restrict__ A,
    const bf16* __restrict__ Bt, OutT* __restrict__ C, int M, int N, int K,
    int RX, int SX, int SY) {
  __shared__ bf16 As[128 * 32];
  __shared__ bf16 Bs[128 * 32];
  const int w   = blockIdx.x;
  const int xcd = w & 7, idx = w >> 3;
  const int rx = xcd % RX, ry = xcd / RX;
  const int bx = rx * SX + idx % SX;
  const int by = ry * SY + idx / SX;
  const int tid  = threadIdx.x;
  const int lane = tid & 63, wid = tid >> 6;
  const int l4 = lane >> 4, l16 = lane & 15;
  const int wr = wid >> 1, wc = wid & 1;
  const int rowBase = by * 128, colBase = bx * 128;

  const bf16* gA = A  + (size_t)(rowBase + (tid >> 2)) * K + (tid & 3) * 8;
  const bf16* gB = Bt + (size_t)(colBase + (tid >> 2)) * K + (tid & 3) * 8;
  const size_t rowStep = (size_t)64 * K;

  f32x4 acc[4][4];
  const f32x4 z = {0.f, 0.f, 0.f, 0.f};
#pragma unroll
  for (int i = 0; i < 4; i++)
#pragma unroll
    for (int j = 0; j < 4; j++) acc[i][j] = z;

  for (int k0 = 0; k0 < K; k0 += 32) {
    __syncthreads();
    gld_lds16(gA + k0,           &As[tid * 8]);
    gld_lds16(gA + rowStep + k0, &As[2048 + tid * 8]);
    gld_lds16(gB + k0,           &Bs[tid * 8]);
    gld_lds16(gB + rowStep + k0, &Bs[2048 + tid * 8]);
    __syncthreads();
    bf16x8 af[4], bfr[4];
#pragma unroll
    for (int mi = 0; mi < 4; mi++)
      af[mi] = *(const bf16x8*)&As[(wr * 64 + mi * 16 + l16) * 32 + l4 * 8];
#pragma unroll
    for (int ni = 0; ni < 4; ni++)
      bfr[ni] = *(const bf16x8*)&Bs[(wc * 64 + ni * 16 + l16) * 32 + l4 * 8];
#pragma unroll
    for (int mi = 0; mi < 4; mi++)
#pragma unroll
      for (int ni = 0; ni < 4; ni++)
        acc[mi][ni] = __builtin_amdgcn_mfma_f32_16x16x32_bf16(af[mi], bfr[ni], acc[mi][ni], 0, 0, 0);
  }
#pragma unroll
  for (int mi = 0; mi < 4; mi++)
#pragma unroll
    for (int ni = 0; ni < 4; ni++) {
      int row = rowBase + wr * 64 + mi * 16 + l4 * 4;
      int col = colBase + wc * 64 + ni * 16 + l16;
#pragma unroll
      for (int r = 0; r < 4; r++)
        C[(size_t)(row + r) * N + col] = (OutT)acc[mi][ni][r];
    }
}

// ---------------- flash attention + ALiBi + causal + silu-gate --------------
// BARRIER-FREE: K/V fragments read directly from L2-resident global (per XCD:
// 4 bh x 1MB = 4MB = one L2).  Only P round-trips through wave-private LDS.
// Grid 1024 = 32 qt x 32 bh; XCD-swizzled, descending-qt launch order.
__global__ __launch_bounds__(256) void attn_kernel(const bf16* __restrict__ qkvp,
    const bf16* __restrict__ ksm, const bf16* __restrict__ vt,
    const float* __restrict__ slopes, bf16* __restrict__ gated) {
  const int w     = blockIdx.x;
  const int xcd   = w & 7, r0 = w >> 3;
  const int bh    = xcd * 4 + (r0 & 3);      // XCD owns 4 bh strips
  const int qtile = 31 - (r0 >> 2);          // long strips dispatch first
  const int b   = bh >> 4, h = bh & 15;
  const int tid = threadIdx.x, wid = tid >> 6, lane = tid & 63;
  const int l4 = lane >> 4, l16 = lane & 15;
  const float LOG2E = 1.44269504f;
  const float s2 = 0.08838834764831845f * LOG2E;   // (1/sqrt(128))*log2e
  const float slopeL = slopes[h] * LOG2E;

  __shared__ bf16 P_lds[64 * 64];   // XOR-swizzled, wave-private rows

  const bf16* ksmB = ksm + (size_t)bh * SEQ * 128;
  const bf16* vtB  = vt  + (size_t)bh * SEQ * 128;

  // Q fragments (rows qtile*64 + wid*16 + l16)
  bf16x8 qf[4];
  {
    const bf16* qrow = qkvp + (size_t)(b * SEQ + qtile * 64 + wid * 16 + l16) * 8192 + h * 128;
#pragma unroll
    for (int kb = 0; kb < 4; kb++) qf[kb] = *(const bf16x8*)(qrow + kb * 32 + l4 * 8);
  }
  f32x4 oacc[8];
  const f32x4 z = {0.f, 0.f, 0.f, 0.f};
#pragma unroll
  for (int i = 0; i < 8; i++) oacc[i] = z;
  float m2[4], lpart[4];
#pragma unroll
  for (int r = 0; r < 4; r++) { m2[r] = -1e38f; lpart[r] = 0.f; }

  const int ntiles = qtile + 1;
  for (int kt = 0; kt < ntiles; ++kt) {
    const bf16* kTile = ksmB + (size_t)kt * 8192;   // [i(64)][d(128)]
    const bf16* vTile = vtB  + (size_t)kt * 8192;   // [d(128)][i(64)]

    // S = Q K^T  (per wave: 16 x 64); K B-frags direct from L2
    f32x4 sacc[4];
#pragma unroll
    for (int jf = 0; jf < 4; jf++) {
      bf16x8 kf[4];
#pragma unroll
      for (int kb = 0; kb < 4; kb++)
        kf[kb] = *(const bf16x8*)(kTile + (jf * 16 + l16) * 128 + kb * 32 + l4 * 8);
      f32x4 a = z;
#pragma unroll
      for (int kb = 0; kb < 4; kb++)
        a = __builtin_amdgcn_mfma_f32_16x16x32_bf16(qf[kb], kf[kb], a, 0, 0, 0);
      sacc[jf] = a;
    }

    // exp2-domain: s*scale*log2e + j*slope*log2e, causal mask on diag tile
    const bool diag = (kt == qtile);
    float sadj[4][4];
#pragma unroll
    for (int jf = 0; jf < 4; jf++) {
      int j = kt * 64 + jf * 16 + l16;
      float bias2 = (float)j * slopeL;
#pragma unroll
      for (int r = 0; r < 4; r++) {
        float v = fmaf(sacc[jf][r], s2, bias2);
        if (diag) {
          int i = qtile * 64 + wid * 16 + l4 * 4 + r;
          if (j > i) v = -1e38f;
        }
        sadj[jf][r] = v;
      }
    }

    // online softmax; rescale only when max grows >14 (wave-uniform branch)
    float p[4][4];
#pragma unroll
    for (int r = 0; r < 4; r++) {
      float mx = fmaxf(fmaxf(sadj[0][r], sadj[1][r]), fmaxf(sadj[2][r], sadj[3][r]));
#pragma unroll
      for (int m = 1; m < 16; m <<= 1) mx = fmaxf(mx, __shfl_xor(mx, m, 64));
      if (__any(mx > m2[r] + 14.f)) {  // uniform: all lanes or none
        float mnew  = fmaxf(m2[r], mx);
        float alpha = exp2f(m2[r] - mnew);
        m2[r] = mnew;
        lpart[r] *= alpha;
#pragma unroll
        for (int df = 0; df < 8; df++) oacc[df][r] *= alpha;
      }
      float rs = 0.f;
#pragma unroll
      for (int jf = 0; jf < 4; jf++) {
        float pe = exp2f(sadj[jf][r] - m2[r]);
        p[jf][r] = pe;
        rs += pe;
      }
      lpart[r] += rs;                // per-lane partial; reduced at end
    }

    // P -> LDS (swizzled, wave-private rows; lgkmcnt orders write->read)
#pragma unroll
    for (int jf = 0; jf < 4; jf++)
#pragma unroll
      for (int r = 0; r < 4; r++) {
        int prow = wid * 16 + l4 * 4 + r;
        P_lds[prow * 64 + ((jf * 16 + l16) ^ ((prow & 7) << 3))] = (bf16)p[jf][r];
      }

    // PV: P A-frags from LDS, V B-frags direct from L2
#pragma unroll
    for (int kb2 = 0; kb2 < 2; ++kb2) {
      const int prow = wid * 16 + l16;
      bf16x8 pf = *(const bf16x8*)&P_lds[prow * 64 + ((kb2 * 32 + l4 * 8) ^ ((prow & 7) << 3))];
#pragma unroll
      for (int df = 0; df < 8; df++) {
        bf16x8 vf = *(const bf16x8*)(vTile + (df * 16 + l16) * 64 + kb2 * 32 + l4 * 8);
        oacc[df] = __builtin_amdgcn_mfma_f32_16x16x32_bf16(pf, vf, oacc[df], 0, 0, 0);
      }
    }
  }

  // epilogue: reduce l partials, normalize, gate with silu(p), store bf16
  float linv[4];
#pragma unroll
  for (int r = 0; r < 4; r++) {
    float lr = lpart[r];
#pragma unroll
    for (int m = 1; m < 16; m <<= 1) lr += __shfl_xor(lr, m, 64);
    linv[r] = 1.f / lr;
  }
#pragma unroll
  for (int df = 0; df < 8; df++) {
    int d = df * 16 + l16;
#pragma unroll
    for (int r = 0; r < 4; r++) {
      int i = qtile * 64 + wid * 16 + l4 * 4 + r;
      float o = oacc[df][r] * linv[r];
      float pg = (float)qkvp[(size_t)(b * SEQ + i) * 8192 + 6144 + h * 128 + d];
      float silu = pg / (1.f + __expf(-pg));
      gated[(size_t)(b * SEQ + i) * 2048 + h * 128 + d] = (bf16)(silu * o);
    }
  }
}

// ---------------------------------------------------------------------------
extern "C" void kernel_launch(void* const* d_in, const int* in_sizes, int n_in,
                              void* d_out, int out_size, void* d_ws, size_t ws_size,
                              hipStream_t stream) {
  (void)in_sizes; (void)n_in; (void)out_size; (void)ws_size;
  const float* x      = (const float*)d_in[0];
  const float* w_in   = (const float*)d_in[1];
  const float* w_out  = (const float*)d_in[2];
  const float* lnig   = (const float*)d_in[3];
  const float* lnib   = (const float*)d_in[4];
  const float* lnog   = (const float*)d_in[5];
  const float* lnob   = (const float*)d_in[6];
  const float* slopes = (const float*)d_in[7];
  const float* smf    = (const float*)d_in[8];
  float* out = (float*)d_out;

  char* ws = (char*)d_ws;
  size_t off = 0;
  bf16* hb      = (bf16*)(ws + off); off += (size_t)4096 * 1024 * 2;  // h (bf16)
  bf16* w_in_b  = (bf16*)(ws + off); off += (size_t)8192 * 1024 * 2;
  bf16* w_out_b = (bf16*)(ws + off); off += (size_t)1024 * 2048 * 2;
  bf16* qkvp    = (bf16*)(ws + off); off += (size_t)4096 * 8192 * 2;
  bf16* ksm     = (bf16*)(ws + off); off += (size_t)32 * 2048 * 128 * 2;
  bf16* gated   = (bf16*)(ws + off); off += (size_t)4096 * 2048 * 2;
  float* yb     = (float*)(ws + off); off += (size_t)4096 * 1024 * 4;
  bf16* vt      = (bf16*)yb;  // alias: vt dead before gemm2 writes yb

  cvt_kernel<<<4096, 256, 0, stream>>>(w_in,  w_in_b,  8388608 / 8);
  cvt_kernel<<<1024, 256, 0, stream>>>(w_out, w_out_b, 2097152 / 8);
  ln_kernel<true><<<4096, 256, 0, stream>>>(x, lnig, lnib, hb);
  gemm_bt<bf16><<<2048, 256, 0, stream>>>(hb, w_in_b, qkvp, 4096, 8192, 1024, 4, 16, 16);
  smear_kernel<<<4096, 256, 0, stream>>>(qkvp, smf, ksm);
  vtrans_kernel<<<dim3(32, 32), 256, 0, stream>>>(qkvp, vt);
  attn_kernel<<<1024, 256, 0, stream>>>(qkvp, ksm, vt, slopes, gated);
  gemm_bt<float><<<256, 256, 0, stream>>>(gated, w_out_b, yb, 4096, 1024, 2048, 1, 8, 4);
  ln_kernel<false><<<4096, 256, 0, stream>>>(yb, lnog, lnob, out);
}

// Round 6
// 260.352 us; speedup vs baseline: 1.6195x; 1.6195x over previous
//
#include <hip/hip_runtime.h>
#include <hip/hip_bf16.h>
#include <stdint.h>

// ---------------------------------------------------------------------------
// Block: LN -> [q,k,v,p] = h @ w_in^T -> key-smear -> causal attn w/ learned
// ALiBi -> o * silu(p) -> @ w_out^T -> LN.   B=2 L=2048 D=1024 H=16 Dh=128.
// Internal compute in bf16 MFMA.
// ---------------------------------------------------------------------------

typedef __bf16 bf16;
typedef bf16  bf16x8 __attribute__((ext_vector_type(8)));
typedef bf16  bf16x4 __attribute__((ext_vector_type(4)));
typedef float f32x4  __attribute__((ext_vector_type(4)));

#define SEQ   2048
#define NBATC 2

__device__ __forceinline__ void gld_lds16(const bf16* g, bf16* l) {
  __builtin_amdgcn_global_load_lds((const __attribute__((address_space(1))) void*)g,
                                   (__attribute__((address_space(3))) void*)l, 16, 0, 0);
}

// ---------------- f32 -> bf16 convert (8 elems/thread) ----------------------
__global__ __launch_bounds__(256) void cvt_kernel(const float* __restrict__ in,
                                                  bf16* __restrict__ out, int n8) {
  int t = blockIdx.x * 256 + threadIdx.x;
  if (t >= n8) return;
  const float4* p = (const float4*)in + (size_t)t * 2;
  float4 a = p[0], b = p[1];
  bf16x8 o;
  o[0] = (bf16)a.x; o[1] = (bf16)a.y; o[2] = (bf16)a.z; o[3] = (bf16)a.w;
  o[4] = (bf16)b.x; o[5] = (bf16)b.y; o[6] = (bf16)b.z; o[7] = (bf16)b.w;
  *((bf16x8*)out + t) = o;
}

// ---------------- LayerNorm over rows of 1024 f32 ---------------------------
template<bool BF16OUT>
__global__ __launch_bounds__(256) void ln_kernel(const float* __restrict__ x,
    const float* __restrict__ gamma, const float* __restrict__ beta,
    void* __restrict__ out) {
  const int row = blockIdx.x;
  const int tid = threadIdx.x;
  float4 v = *(const float4*)(x + (size_t)row * 1024 + tid * 4);
  float s  = v.x + v.y + v.z + v.w;
  float ss = v.x * v.x + v.y * v.y + v.z * v.z + v.w * v.w;
#pragma unroll
  for (int m = 1; m < 64; m <<= 1) { s += __shfl_xor(s, m, 64); ss += __shfl_xor(ss, m, 64); }
  __shared__ float red[8];
  if ((tid & 63) == 0) { red[tid >> 6] = s; red[(tid >> 6) + 4] = ss; }
  __syncthreads();
  s  = red[0] + red[1] + red[2] + red[3];
  ss = red[4] + red[5] + red[6] + red[7];
  const float mu  = s * (1.f / 1024.f);
  const float inv = rsqrtf(ss * (1.f / 1024.f) - mu * mu + 1e-5f);
  float4 g  = *(const float4*)(gamma + tid * 4);
  float4 bb = *(const float4*)(beta  + tid * 4);
  float y0 = (v.x - mu) * inv * g.x + bb.x;
  float y1 = (v.y - mu) * inv * g.y + bb.y;
  float y2 = (v.z - mu) * inv * g.z + bb.z;
  float y3 = (v.w - mu) * inv * g.w + bb.w;
  if (BF16OUT) {
    bf16* o = (bf16*)out + (size_t)row * 1024 + tid * 4;
    o[0] = (bf16)y0; o[1] = (bf16)y1; o[2] = (bf16)y2; o[3] = (bf16)y3;
  } else {
    float* o = (float*)out + (size_t)row * 1024 + tid * 4;
    o[0] = y0; o[1] = y1; o[2] = y2; o[3] = y3;
  }
}

// ---------------- key smear -> ksm, stored XOR-swizzled ---------------------
// physical idx within row i: (d) ^ ((i&7)<<3)  (8-elem granularity)
__global__ __launch_bounds__(256) void smear_kernel(const bf16* __restrict__ qkvp,
    const float* __restrict__ smf, bf16* __restrict__ ksm) {
  int t  = blockIdx.x * 256 + threadIdx.x;   // 2^20 vec8 groups
  int d8 = t & 15;
  int i  = (t >> 4) & 2047;
  int h  = (t >> 15) & 15;
  int b  = t >> 19;
  float sm = 1.f / (1.f + __expf(-smf[h]));
  const bf16* base = qkvp + (size_t)(b * SEQ + i) * 8192 + 2048 + h * 128 + d8 * 8;
  bf16x8 cur = *(const bf16x8*)base;
  bf16x8 prv = cur;
  if (i > 0) prv = *(const bf16x8*)(base - 8192);
  bf16x8 o;
#pragma unroll
  for (int e = 0; e < 8; e++) {
    float pv = (i > 0) ? (float)prv[e] : 0.f;
    o[e] = (bf16)((1.f - sm) * (float)cur[e] + sm * pv);
  }
  size_t idx = ((size_t)(b * 16 + h) * SEQ + i) * 128 + ((d8 * 8) ^ ((i & 7) << 3));
  *(bf16x8*)(ksm + idx) = o;
}

// ---------------- V transpose: vt[bh][kt][d][i0..63], XOR-swizzled ----------
__global__ __launch_bounds__(256) void vtrans_kernel(const bf16* __restrict__ qkvp,
                                                     bf16* __restrict__ vt) {
  __shared__ bf16 T[128][72];
  const int kt = blockIdx.x, bh = blockIdx.y;
  const int b = bh >> 4, h = bh & 15;
  const int t = threadIdx.x;
  {
    int i = t >> 2, d0 = (t & 3) * 32;
    const bf16* src = qkvp + (size_t)(b * SEQ + kt * 64 + i) * 8192 + 4096 + h * 128 + d0;
#pragma unroll
    for (int m = 0; m < 4; m++) {
      bf16x8 v8 = *(const bf16x8*)(src + m * 8);
#pragma unroll
      for (int e = 0; e < 8; e++) T[d0 + m * 8 + e][i] = v8[e];
    }
  }
  __syncthreads();
  {
    int d = t >> 1, i0 = (t & 1) * 32;
    bf16* dst = vt + (size_t)bh * (SEQ * 128) + (size_t)kt * 8192 + d * 64;
#pragma unroll
    for (int m = 0; m < 4; m++) {
      bf16x8 v8 = *(const bf16x8*)&T[d][i0 + m * 8];
      *(bf16x8*)(dst + (((i0 + m * 8)) ^ ((d & 7) << 3))) = v8;
    }
  }
}

// ---------------- GEMM: C[M][N] = A[M][K] * Bt[N][K]^T  (bf16 MFMA) ---------
template<typename OutT>
__global__ __launch_bounds__(256) void gemm_bt(const bf16* __restrict__ A,
    const bf16* __restrict__ Bt, OutT* __restrict__ C, int M, int N, int K,
    int RX, int SX, int SY) {
  __shared__ bf16 As[128 * 32];
  __shared__ bf16 Bs[128 * 32];
  const int w   = blockIdx.x;
  const int xcd = w & 7, idx = w >> 3;
  const int rx = xcd % RX, ry = xcd / RX;
  const int bx = rx * SX + idx % SX;
  const int by = ry * SY + idx / SX;
  const int tid  = threadIdx.x;
  const int lane = tid & 63, wid = tid >> 6;
  const int l4 = lane >> 4, l16 = lane & 15;
  const int wr = wid >> 1, wc = wid & 1;
  const int rowBase = by * 128, colBase = bx * 128;

  const bf16* gA = A  + (size_t)(rowBase + (tid >> 2)) * K + (tid & 3) * 8;
  const bf16* gB = Bt + (size_t)(colBase + (tid >> 2)) * K + (tid & 3) * 8;
  const size_t rowStep = (size_t)64 * K;

  f32x4 acc[4][4];
  const f32x4 z = {0.f, 0.f, 0.f, 0.f};
#pragma unroll
  for (int i = 0; i < 4; i++)
#pragma unroll
    for (int j = 0; j < 4; j++) acc[i][j] = z;

  for (int k0 = 0; k0 < K; k0 += 32) {
    __syncthreads();
    gld_lds16(gA + k0,           &As[tid * 8]);
    gld_lds16(gA + rowStep + k0, &As[2048 + tid * 8]);
    gld_lds16(gB + k0,           &Bs[tid * 8]);
    gld_lds16(gB + rowStep + k0, &Bs[2048 + tid * 8]);
    __syncthreads();
    bf16x8 af[4], bfr[4];
#pragma unroll
    for (int mi = 0; mi < 4; mi++)
      af[mi] = *(const bf16x8*)&As[(wr * 64 + mi * 16 + l16) * 32 + l4 * 8];
#pragma unroll
    for (int ni = 0; ni < 4; ni++)
      bfr[ni] = *(const bf16x8*)&Bs[(wc * 64 + ni * 16 + l16) * 32 + l4 * 8];
#pragma unroll
    for (int mi = 0; mi < 4; mi++)
#pragma unroll
      for (int ni = 0; ni < 4; ni++)
        acc[mi][ni] = __builtin_amdgcn_mfma_f32_16x16x32_bf16(af[mi], bfr[ni], acc[mi][ni], 0, 0, 0);
  }
#pragma unroll
  for (int mi = 0; mi < 4; mi++)
#pragma unroll
    for (int ni = 0; ni < 4; ni++) {
      int row = rowBase + wr * 64 + mi * 16 + l4 * 4;
      int col = colBase + wc * 64 + ni * 16 + l16;
#pragma unroll
      for (int r = 0; r < 4; r++)
        C[(size_t)(row + r) * N + col] = (OutT)acc[mi][ni][r];
    }
}

// ---------------- flash attention + ALiBi + causal + silu-gate --------------
// Swapped-QK^T: S^T = mfma(K,Q) so each lane owns ONE q-row (i = l16):
// scalar m/l, lane-local rescale, 2-shuffle max, b64 P writes, O^T epilogue.
// Dbuf global_load_lds staging from pre-swizzled globals; paired strips;
// XCD-swizzled grid (4 bh per XCD -> K/V strips L2-resident).
__global__ __launch_bounds__(256) void attn_kernel(const bf16* __restrict__ qkvp,
    const bf16* __restrict__ ksm, const bf16* __restrict__ vt,
    const float* __restrict__ slopes, bf16* __restrict__ gated) {
  const int w   = blockIdx.x;                // 512
  const int l   = (w & 7) * 64 + (w >> 3);   // XCD j -> bh in [4j, 4j+4)
  const int qp  = l & 15;
  const int bh  = l >> 4;
  const int b   = bh >> 4, h = bh & 15;
  const int tid = threadIdx.x, wid = tid >> 6, lane = tid & 63;
  const int l4 = lane >> 4, l16 = lane & 15;
  const int swz = (l16 & 7) << 3;
  const float LOG2E = 1.44269504f;
  const float s2 = 0.08838834764831845f * LOG2E;   // (1/sqrt(128))*log2e
  const float slopeL = slopes[h] * LOG2E;

  __shared__ bf16 Kb[2][64 * 128];
  __shared__ bf16 Vb[2][64 * 128];
  __shared__ bf16 P_lds[64 * 64];   // [i][k ^ ((i&7)<<3)], wave-private rows

  const bf16* ksmB = ksm + (size_t)bh * SEQ * 128;
  const bf16* vtB  = vt  + (size_t)bh * SEQ * 128;

  auto stage = [&](int kt, int bsel) {
    const bf16* ks = ksmB + kt * 8192 + tid * 8;
    const bf16* vs = vtB  + kt * 8192 + tid * 8;
    bf16* kd = &Kb[bsel][tid * 8];
    bf16* vd = &Vb[bsel][tid * 8];
#pragma unroll
    for (int g = 0; g < 4; g++) {
      gld_lds16(ks + g * 2048, kd + g * 2048);
      gld_lds16(vs + g * 2048, vd + g * 2048);
    }
  };

  auto run_strip = [&](int qtile, int ntiles) {
    const int iq = qtile * 64 + wid * 16 + l16;   // this lane's q-row
    bf16x8 qf[4];
    {
      const bf16* qrow = qkvp + (size_t)(b * SEQ + iq) * 8192 + h * 128;
#pragma unroll
      for (int kb = 0; kb < 4; kb++) qf[kb] = *(const bf16x8*)(qrow + kb * 32 + l4 * 8);
    }
    f32x4 oacc[8];   // oacc[df][r] = O[iq][df*16 + l4*4 + r]
    const f32x4 z = {0.f, 0.f, 0.f, 0.f};
#pragma unroll
    for (int i = 0; i < 8; i++) oacc[i] = z;
    float m2 = -1e38f, lpart = 0.f;

    stage(0, 0);
    for (int t = 0; t < ntiles; ++t) {
      __syncthreads();                     // drains tile-t loads (vmcnt)
      if (t + 1 < ntiles) stage(t + 1, (t + 1) & 1);   // prefetch overlaps compute
      const bf16* K_ = Kb[t & 1];
      const bf16* V_ = Vb[t & 1];
      const int kt = t;

      // S^T = K Q^T per wave: sacc[jf][r] = S[iq][kt*64 + jf*16 + l4*4 + r]
      f32x4 sacc[4];
#pragma unroll
      for (int jf = 0; jf < 4; jf++) {
        bf16x8 kf[4];
#pragma unroll
        for (int kb = 0; kb < 4; kb++)
          kf[kb] = *(const bf16x8*)&K_[(jf * 16 + l16) * 128 + ((kb * 32 + l4 * 8) ^ swz)];
        f32x4 a = z;
#pragma unroll
        for (int kb = 0; kb < 4; kb++)
          a = __builtin_amdgcn_mfma_f32_16x16x32_bf16(kf[kb], qf[kb], a, 0, 0, 0);
        sacc[jf] = a;
      }

      // exp2-domain bias + causal mask (j from row index now)
      const bool diag = (kt == qtile);
      const int kbase = kt * 64 + l4 * 4;
      float sadj[4][4];
#pragma unroll
      for (int jf = 0; jf < 4; jf++) {
#pragma unroll
        for (int r = 0; r < 4; r++) {
          int j = kbase + jf * 16 + r;
          float v = fmaf(sacc[jf][r], s2, (float)j * slopeL);
          if (diag && j > iq) v = -1e38f;
          sadj[jf][r] = v;
        }
      }

      // row max: lane-local 16 + 2 shuffles (lanes sharing l16 hold the row)
      float mx = sadj[0][0];
#pragma unroll
      for (int jf = 0; jf < 4; jf++)
#pragma unroll
        for (int r = 0; r < 4; r++) mx = fmaxf(mx, sadj[jf][r]);
      mx = fmaxf(mx, __shfl_xor(mx, 16, 64));
      mx = fmaxf(mx, __shfl_xor(mx, 32, 64));

      if (__any(mx > m2 + 14.f)) {         // uniform defer-max rescale
        float mnew  = fmaxf(m2, mx);
        float alpha = __builtin_amdgcn_exp2f(m2 - mnew);
        m2 = mnew;
        lpart *= alpha;
#pragma unroll
        for (int df = 0; df < 8; df++) oacc[df] *= alpha;
      }

      // P = exp2(S - m), packed b64 writes into swizzled wave-private rows
      float rs = 0.f;
#pragma unroll
      for (int jf = 0; jf < 4; jf++) {
        bf16x4 pw;
#pragma unroll
        for (int r = 0; r < 4; r++) {
          float pe = __builtin_amdgcn_exp2f(sadj[jf][r] - m2);
          rs += pe;
          pw[r] = (bf16)pe;
        }
        *(bf16x4*)&P_lds[(wid * 16 + l16) * 64 + ((jf * 16 + l4 * 4) ^ swz)] = pw;
      }
      lpart += rs;

      // PV: O^T = mfma(Vt, P) -> D[col=l16=i][row=l4*4+r=d-sub]
#pragma unroll
      for (int kb2 = 0; kb2 < 2; ++kb2) {
        bf16x8 pf = *(const bf16x8*)&P_lds[(wid * 16 + l16) * 64 + ((kb2 * 32 + l4 * 8) ^ swz)];
#pragma unroll
        for (int df = 0; df < 8; df++) {
          bf16x8 vf = *(const bf16x8*)&V_[(df * 16 + l16) * 64 + ((kb2 * 32 + l4 * 8) ^ swz)];
          oacc[df] = __builtin_amdgcn_mfma_f32_16x16x32_bf16(vf, pf, oacc[df], 0, 0, 0);
        }
      }
    }

    // epilogue: finish l, normalize, silu-gate, vectorized 8B stores
    lpart += __shfl_xor(lpart, 16, 64);
    lpart += __shfl_xor(lpart, 32, 64);
    const float linv = 1.f / lpart;
    const bf16* pgrow = qkvp + (size_t)(b * SEQ + iq) * 8192 + 6144 + h * 128;
    bf16* grow = gated + (size_t)(b * SEQ + iq) * 2048 + h * 128;
#pragma unroll
    for (int df = 0; df < 8; df++) {
      const int d0 = df * 16 + l4 * 4;
      bf16x4 pg4 = *(const bf16x4*)(pgrow + d0);
      bf16x4 o4;
#pragma unroll
      for (int r = 0; r < 4; r++) {
        float o  = oacc[df][r] * linv;
        float pg = (float)pg4[r];
        float silu = pg / (1.f + __expf(-pg));
        o4[r] = (bf16)(silu * o);
      }
      *(bf16x4*)(grow + d0) = o4;
    }
  };

  run_strip(qp, qp + 1);
  __syncthreads();        // protect Kb[0]/Vb[0] before strip B's prologue stage
  run_strip(31 - qp, 32 - qp);
}

// ---------------------------------------------------------------------------
extern "C" void kernel_launch(void* const* d_in, const int* in_sizes, int n_in,
                              void* d_out, int out_size, void* d_ws, size_t ws_size,
                              hipStream_t stream) {
  (void)in_sizes; (void)n_in; (void)out_size; (void)ws_size;
  const float* x      = (const float*)d_in[0];
  const float* w_in   = (const float*)d_in[1];
  const float* w_out  = (const float*)d_in[2];
  const float* lnig   = (const float*)d_in[3];
  const float* lnib   = (const float*)d_in[4];
  const float* lnog   = (const float*)d_in[5];
  const float* lnob   = (const float*)d_in[6];
  const float* slopes = (const float*)d_in[7];
  const float* smf    = (const float*)d_in[8];
  float* out = (float*)d_out;

  char* ws = (char*)d_ws;
  size_t off = 0;
  bf16* hb      = (bf16*)(ws + off); off += (size_t)4096 * 1024 * 2;  // h (bf16)
  bf16* w_in_b  = (bf16*)(ws + off); off += (size_t)8192 * 1024 * 2;
  bf16* w_out_b = (bf16*)(ws + off); off += (size_t)1024 * 2048 * 2;
  bf16* qkvp    = (bf16*)(ws + off); off += (size_t)4096 * 8192 * 2;
  bf16* ksm     = (bf16*)(ws + off); off += (size_t)32 * 2048 * 128 * 2;
  bf16* gated   = (bf16*)(ws + off); off += (size_t)4096 * 2048 * 2;
  float* yb     = (float*)(ws + off); off += (size_t)4096 * 1024 * 4;
  bf16* vt      = (bf16*)yb;  // alias: vt dead before gemm2 writes yb

  cvt_kernel<<<4096, 256, 0, stream>>>(w_in,  w_in_b,  8388608 / 8);
  cvt_kernel<<<1024, 256, 0, stream>>>(w_out, w_out_b, 2097152 / 8);
  ln_kernel<true><<<4096, 256, 0, stream>>>(x, lnig, lnib, hb);
  gemm_bt<bf16><<<2048, 256, 0, stream>>>(hb, w_in_b, qkvp, 4096, 8192, 1024, 4, 16, 16);
  smear_kernel<<<4096, 256, 0, stream>>>(qkvp, smf, ksm);
  vtrans_kernel<<<dim3(32, 32), 256, 0, stream>>>(qkvp, vt);
  attn_kernel<<<512, 256, 0, stream>>>(qkvp, ksm, vt, slopes, gated);
  gemm_bt<float><<<256, 256, 0, stream>>>(gated, w_out_b, yb, 4096, 1024, 2048, 1, 8, 4);
  ln_kernel<false><<<4096, 256, 0, stream>>>(yb, lnog, lnob, out);
}

// Round 7
// 241.448 us; speedup vs baseline: 1.7463x; 1.0783x over previous
//
#include <hip/hip_runtime.h>
#include <hip/hip_bf16.h>
#include <stdint.h>

// ---------------------------------------------------------------------------
// Block: LN -> [q,k,v,p] = h @ w_in^T -> key-smear -> causal attn w/ learned
// ALiBi -> o * silu(p) -> @ w_out^T -> LN.   B=2 L=2048 D=1024 H=16 Dh=128.
// Internal compute in bf16 MFMA.
// ---------------------------------------------------------------------------

typedef __bf16 bf16;
typedef bf16  bf16x8 __attribute__((ext_vector_type(8)));
typedef bf16  bf16x4 __attribute__((ext_vector_type(4)));
typedef float f32x4  __attribute__((ext_vector_type(4)));

#define SEQ   2048
#define NBATC 2

__device__ __forceinline__ void gld_lds16(const bf16* g, bf16* l) {
  __builtin_amdgcn_global_load_lds((const __attribute__((address_space(1))) void*)g,
                                   (__attribute__((address_space(3))) void*)l, 16, 0, 0);
}

// ---------------- f32 -> bf16 convert (8 elems/thread) ----------------------
__global__ __launch_bounds__(256) void cvt_kernel(const float* __restrict__ in,
                                                  bf16* __restrict__ out, int n8) {
  int t = blockIdx.x * 256 + threadIdx.x;
  if (t >= n8) return;
  const float4* p = (const float4*)in + (size_t)t * 2;
  float4 a = p[0], b = p[1];
  bf16x8 o;
  o[0] = (bf16)a.x; o[1] = (bf16)a.y; o[2] = (bf16)a.z; o[3] = (bf16)a.w;
  o[4] = (bf16)b.x; o[5] = (bf16)b.y; o[6] = (bf16)b.z; o[7] = (bf16)b.w;
  *((bf16x8*)out + t) = o;
}

// ---------------- LayerNorm over rows of 1024 f32 ---------------------------
template<bool BF16OUT>
__global__ __launch_bounds__(256) void ln_kernel(const float* __restrict__ x,
    const float* __restrict__ gamma, const float* __restrict__ beta,
    void* __restrict__ out) {
  const int row = blockIdx.x;
  const int tid = threadIdx.x;
  float4 v = *(const float4*)(x + (size_t)row * 1024 + tid * 4);
  float s  = v.x + v.y + v.z + v.w;
  float ss = v.x * v.x + v.y * v.y + v.z * v.z + v.w * v.w;
#pragma unroll
  for (int m = 1; m < 64; m <<= 1) { s += __shfl_xor(s, m, 64); ss += __shfl_xor(ss, m, 64); }
  __shared__ float red[8];
  if ((tid & 63) == 0) { red[tid >> 6] = s; red[(tid >> 6) + 4] = ss; }
  __syncthreads();
  s  = red[0] + red[1] + red[2] + red[3];
  ss = red[4] + red[5] + red[6] + red[7];
  const float mu  = s * (1.f / 1024.f);
  const float inv = rsqrtf(ss * (1.f / 1024.f) - mu * mu + 1e-5f);
  float4 g  = *(const float4*)(gamma + tid * 4);
  float4 bb = *(const float4*)(beta  + tid * 4);
  float y0 = (v.x - mu) * inv * g.x + bb.x;
  float y1 = (v.y - mu) * inv * g.y + bb.y;
  float y2 = (v.z - mu) * inv * g.z + bb.z;
  float y3 = (v.w - mu) * inv * g.w + bb.w;
  if (BF16OUT) {
    bf16* o = (bf16*)out + (size_t)row * 1024 + tid * 4;
    o[0] = (bf16)y0; o[1] = (bf16)y1; o[2] = (bf16)y2; o[3] = (bf16)y3;
  } else {
    float* o = (float*)out + (size_t)row * 1024 + tid * 4;
    o[0] = y0; o[1] = y1; o[2] = y2; o[3] = y3;
  }
}

// ---------------- key smear -> ksm, stored XOR-swizzled ---------------------
// physical idx within row i: (d) ^ ((i&7)<<3)  (8-elem granularity)
__global__ __launch_bounds__(256) void smear_kernel(const bf16* __restrict__ qkvp,
    const float* __restrict__ smf, bf16* __restrict__ ksm) {
  int t  = blockIdx.x * 256 + threadIdx.x;   // 2^20 vec8 groups
  int d8 = t & 15;
  int i  = (t >> 4) & 2047;
  int h  = (t >> 15) & 15;
  int b  = t >> 19;
  float sm = 1.f / (1.f + __expf(-smf[h]));
  const bf16* base = qkvp + (size_t)(b * SEQ + i) * 8192 + 2048 + h * 128 + d8 * 8;
  bf16x8 cur = *(const bf16x8*)base;
  bf16x8 prv = cur;
  if (i > 0) prv = *(const bf16x8*)(base - 8192);
  bf16x8 o;
#pragma unroll
  for (int e = 0; e < 8; e++) {
    float pv = (i > 0) ? (float)prv[e] : 0.f;
    o[e] = (bf16)((1.f - sm) * (float)cur[e] + sm * pv);
  }
  size_t idx = ((size_t)(b * 16 + h) * SEQ + i) * 128 + ((d8 * 8) ^ ((i & 7) << 3));
  *(bf16x8*)(ksm + idx) = o;
}

// ---------------- V transpose: vt[bh][kt][d][i0..63], XOR-swizzled ----------
__global__ __launch_bounds__(256) void vtrans_kernel(const bf16* __restrict__ qkvp,
                                                     bf16* __restrict__ vt) {
  __shared__ bf16 T[128][72];
  const int kt = blockIdx.x, bh = blockIdx.y;
  const int b = bh >> 4, h = bh & 15;
  const int t = threadIdx.x;
  {
    int i = t >> 2, d0 = (t & 3) * 32;
    const bf16* src = qkvp + (size_t)(b * SEQ + kt * 64 + i) * 8192 + 4096 + h * 128 + d0;
#pragma unroll
    for (int m = 0; m < 4; m++) {
      bf16x8 v8 = *(const bf16x8*)(src + m * 8);
#pragma unroll
      for (int e = 0; e < 8; e++) T[d0 + m * 8 + e][i] = v8[e];
    }
  }
  __syncthreads();
  {
    int d = t >> 1, i0 = (t & 1) * 32;
    bf16* dst = vt + (size_t)bh * (SEQ * 128) + (size_t)kt * 8192 + d * 64;
#pragma unroll
    for (int m = 0; m < 4; m++) {
      bf16x8 v8 = *(const bf16x8*)&T[d][i0 + m * 8];
      *(bf16x8*)(dst + (((i0 + m * 8)) ^ ((d & 7) << 3))) = v8;
    }
  }
}

// ---------------- GEMM 256x256 tile, BK=64, counted-vmcnt pipeline ----------
// 8 waves (2M x 4N), 512 threads.  Per K-tile: issue next tile's 8
// global_load_lds FIRST, then s_waitcnt vmcnt(8) (waits current tile only;
// prefetch stays in flight across the 64-MFMA compute), raw s_barrier (no
// __syncthreads vmcnt(0) drain).  LDS XOR-swizzled via pre-swizzled global
// source + swizzled ds_read (involution, 2 lanes/bank = free).
__global__ __launch_bounds__(512) void gemm256(const bf16* __restrict__ A,
    const bf16* __restrict__ Bt, bf16* __restrict__ C, int M, int N, int K,
    int RX, int SX, int SY) {
  __shared__ bf16 As[2][256 * 64];
  __shared__ bf16 Bs[2][256 * 64];
  const int w   = blockIdx.x;
  const int xcd = w & 7, idx = w >> 3;
  const int rx = xcd % RX, ry = xcd / RX;
  const int bx = rx * SX + idx % SX;
  const int by = ry * SY + idx / SX;
  const int tid  = threadIdx.x;
  const int lane = tid & 63, wid = tid >> 6;
  const int l4 = lane >> 4, l16 = lane & 15;
  const int wr = wid >> 2, wc = wid & 3;          // 2 x 4 waves
  const int rowBase = by * 256, colBase = bx * 256;
  const int NT = K >> 6;

  f32x4 acc[8][4];
  const f32x4 z = {0.f, 0.f, 0.f, 0.f};
#pragma unroll
  for (int i = 0; i < 8; i++)
#pragma unroll
    for (int j = 0; j < 4; j++) acc[i][j] = z;

  auto stage = [&](int kt, int bsel) {
    const int k0 = kt * 64;
    bf16* ad = &As[bsel][tid * 8];
    bf16* bd = &Bs[bsel][tid * 8];
#pragma unroll
    for (int j = 0; j < 4; ++j) {
      const int c   = j * 512 + tid;       // 16-B chunk index (2048 total)
      const int row = c >> 3;              // 0..255
      const int sc  = ((c & 7) * 8) ^ ((row & 7) << 3);   // pre-swizzled src col
      gld_lds16(A  + (size_t)(rowBase + row) * K + k0 + sc, ad + j * 4096);
      gld_lds16(Bt + (size_t)(colBase + row) * K + k0 + sc, bd + j * 4096);
    }
  };

  stage(0, 0);
  for (int t = 0; t < NT; ++t) {
    const int cur = t & 1;
    if (t + 1 < NT) {
      stage(t + 1, cur ^ 1);                                   // 8 loads in flight
      asm volatile("s_waitcnt vmcnt(8)" ::: "memory");         // tile t done only
    } else {
      asm volatile("s_waitcnt vmcnt(0)" ::: "memory");
    }
    asm volatile("s_barrier" ::: "memory");                    // raw: no drain
    const bf16* a_ = &As[cur][0];
    const bf16* b_ = &Bs[cur][0];
#pragma unroll
    for (int ks = 0; ks < 2; ++ks) {
      bf16x8 bfr[4];
#pragma unroll
      for (int ni = 0; ni < 4; ++ni) {
        const int br = wc * 64 + ni * 16 + l16;
        bfr[ni] = *(const bf16x8*)&b_[br * 64 + ((ks * 32 + l4 * 8) ^ ((br & 7) << 3))];
      }
#pragma unroll
      for (int mi = 0; mi < 8; ++mi) {
        const int ar = wr * 128 + mi * 16 + l16;
        bf16x8 af = *(const bf16x8*)&a_[ar * 64 + ((ks * 32 + l4 * 8) ^ ((ar & 7) << 3))];
#pragma unroll
        for (int ni = 0; ni < 4; ++ni)
          acc[mi][ni] = __builtin_amdgcn_mfma_f32_16x16x32_bf16(af, bfr[ni], acc[mi][ni], 0, 0, 0);
      }
    }
    asm volatile("s_waitcnt lgkmcnt(0)" ::: "memory");   // LDS reads done
    asm volatile("s_barrier" ::: "memory");              // before next overwrite
  }

#pragma unroll
  for (int mi = 0; mi < 8; ++mi)
#pragma unroll
    for (int ni = 0; ni < 4; ++ni) {
      int row = rowBase + wr * 128 + mi * 16 + l4 * 4;
      int col = colBase + wc * 64 + ni * 16 + l16;
#pragma unroll
      for (int r = 0; r < 4; ++r)
        C[(size_t)(row + r) * N + col] = (bf16)acc[mi][ni][r];
    }
}

// ---------------- GEMM: C[M][N] = A[M][K] * Bt[N][K]^T  (128² fallback) -----
template<typename OutT>
__global__ __launch_bounds__(256) void gemm_bt(const bf16* __restrict__ A,
    const bf16* __restrict__ Bt, OutT* __restrict__ C, int M, int N, int K,
    int RX, int SX, int SY) {
  __shared__ bf16 As[128 * 32];
  __shared__ bf16 Bs[128 * 32];
  const int w   = blockIdx.x;
  const int xcd = w & 7, idx = w >> 3;
  const int rx = xcd % RX, ry = xcd / RX;
  const int bx = rx * SX + idx % SX;
  const int by = ry * SY + idx / SX;
  const int tid  = threadIdx.x;
  const int lane = tid & 63, wid = tid >> 6;
  const int l4 = lane >> 4, l16 = lane & 15;
  const int wr = wid >> 1, wc = wid & 1;
  const int rowBase = by * 128, colBase = bx * 128;

  const bf16* gA = A  + (size_t)(rowBase + (tid >> 2)) * K + (tid & 3) * 8;
  const bf16* gB = Bt + (size_t)(colBase + (tid >> 2)) * K + (tid & 3) * 8;
  const size_t rowStep = (size_t)64 * K;

  f32x4 acc[4][4];
  const f32x4 z = {0.f, 0.f, 0.f, 0.f};
#pragma unroll
  for (int i = 0; i < 4; i++)
#pragma unroll
    for (int j = 0; j < 4; j++) acc[i][j] = z;

  for (int k0 = 0; k0 < K; k0 += 32) {
    __syncthreads();
    gld_lds16(gA + k0,           &As[tid * 8]);
    gld_lds16(gA + rowStep + k0, &As[2048 + tid * 8]);
    gld_lds16(gB + k0,           &Bs[tid * 8]);
    gld_lds16(gB + rowStep + k0, &Bs[2048 + tid * 8]);
    __syncthreads();
    bf16x8 af[4], bfr[4];
#pragma unroll
    for (int mi = 0; mi < 4; mi++)
      af[mi] = *(const bf16x8*)&As[(wr * 64 + mi * 16 + l16) * 32 + l4 * 8];
#pragma unroll
    for (int ni = 0; ni < 4; ni++)
      bfr[ni] = *(const bf16x8*)&Bs[(wc * 64 + ni * 16 + l16) * 32 + l4 * 8];
#pragma unroll
    for (int mi = 0; mi < 4; mi++)
#pragma unroll
      for (int ni = 0; ni < 4; ni++)
        acc[mi][ni] = __builtin_amdgcn_mfma_f32_16x16x32_bf16(af[mi], bfr[ni], acc[mi][ni], 0, 0, 0);
  }
#pragma unroll
  for (int mi = 0; mi < 4; mi++)
#pragma unroll
    for (int ni = 0; ni < 4; ni++) {
      int row = rowBase + wr * 64 + mi * 16 + l4 * 4;
      int col = colBase + wc * 64 + ni * 16 + l16;
#pragma unroll
      for (int r = 0; r < 4; r++)
        C[(size_t)(row + r) * N + col] = (OutT)acc[mi][ni][r];
    }
}

// ---------------- flash attention + ALiBi + causal + silu-gate --------------
// Swapped-QK^T: S^T = mfma(K,Q) so each lane owns ONE q-row (i = l16):
// scalar m/l, lane-local rescale, 2-shuffle max, b64 P writes, O^T epilogue.
__global__ __launch_bounds__(256) void attn_kernel(const bf16* __restrict__ qkvp,
    const bf16* __restrict__ ksm, const bf16* __restrict__ vt,
    const float* __restrict__ slopes, bf16* __restrict__ gated) {
  const int w   = blockIdx.x;                // 512
  const int l   = (w & 7) * 64 + (w >> 3);   // XCD j -> bh in [4j, 4j+4)
  const int qp  = l & 15;
  const int bh  = l >> 4;
  const int b   = bh >> 4, h = bh & 15;
  const int tid = threadIdx.x, wid = tid >> 6, lane = tid & 63;
  const int l4 = lane >> 4, l16 = lane & 15;
  const int swz = (l16 & 7) << 3;
  const float LOG2E = 1.44269504f;
  const float s2 = 0.08838834764831845f * LOG2E;   // (1/sqrt(128))*log2e
  const float slopeL = slopes[h] * LOG2E;

  __shared__ bf16 Kb[2][64 * 128];
  __shared__ bf16 Vb[2][64 * 128];
  __shared__ bf16 P_lds[64 * 64];   // [i][k ^ ((i&7)<<3)], wave-private rows

  const bf16* ksmB = ksm + (size_t)bh * SEQ * 128;
  const bf16* vtB  = vt  + (size_t)bh * SEQ * 128;

  auto stage = [&](int kt, int bsel) {
    const bf16* ks = ksmB + kt * 8192 + tid * 8;
    const bf16* vs = vtB  + kt * 8192 + tid * 8;
    bf16* kd = &Kb[bsel][tid * 8];
    bf16* vd = &Vb[bsel][tid * 8];
#pragma unroll
    for (int g = 0; g < 4; g++) {
      gld_lds16(ks + g * 2048, kd + g * 2048);
      gld_lds16(vs + g * 2048, vd + g * 2048);
    }
  };

  auto run_strip = [&](int qtile, int ntiles) {
    const int iq = qtile * 64 + wid * 16 + l16;   // this lane's q-row
    bf16x8 qf[4];
    {
      const bf16* qrow = qkvp + (size_t)(b * SEQ + iq) * 8192 + h * 128;
#pragma unroll
      for (int kb = 0; kb < 4; kb++) qf[kb] = *(const bf16x8*)(qrow + kb * 32 + l4 * 8);
    }
    f32x4 oacc[8];   // oacc[df][r] = O[iq][df*16 + l4*4 + r]
    const f32x4 z = {0.f, 0.f, 0.f, 0.f};
#pragma unroll
    for (int i = 0; i < 8; i++) oacc[i] = z;
    float m2 = -1e38f, lpart = 0.f;

    stage(0, 0);
    for (int t = 0; t < ntiles; ++t) {
      __syncthreads();                     // drains tile-t loads (vmcnt)
      if (t + 1 < ntiles) stage(t + 1, (t + 1) & 1);   // prefetch overlaps compute
      const bf16* K_ = Kb[t & 1];
      const bf16* V_ = Vb[t & 1];
      const int kt = t;

      // S^T = K Q^T per wave: sacc[jf][r] = S[iq][kt*64 + jf*16 + l4*4 + r]
      f32x4 sacc[4];
#pragma unroll
      for (int jf = 0; jf < 4; jf++) {
        bf16x8 kf[4];
#pragma unroll
        for (int kb = 0; kb < 4; kb++)
          kf[kb] = *(const bf16x8*)&K_[(jf * 16 + l16) * 128 + ((kb * 32 + l4 * 8) ^ swz)];
        f32x4 a = z;
#pragma unroll
        for (int kb = 0; kb < 4; kb++)
          a = __builtin_amdgcn_mfma_f32_16x16x32_bf16(kf[kb], qf[kb], a, 0, 0, 0);
        sacc[jf] = a;
      }

      // exp2-domain bias + causal mask (j from row index now)
      const bool diag = (kt == qtile);
      const int kbase = kt * 64 + l4 * 4;
      float sadj[4][4];
#pragma unroll
      for (int jf = 0; jf < 4; jf++) {
#pragma unroll
        for (int r = 0; r < 4; r++) {
          int j = kbase + jf * 16 + r;
          float v = fmaf(sacc[jf][r], s2, (float)j * slopeL);
          if (diag && j > iq) v = -1e38f;
          sadj[jf][r] = v;
        }
      }

      // row max: lane-local 16 + 2 shuffles (lanes sharing l16 hold the row)
      float mx = sadj[0][0];
#pragma unroll
      for (int jf = 0; jf < 4; jf++)
#pragma unroll
        for (int r = 0; r < 4; r++) mx = fmaxf(mx, sadj[jf][r]);
      mx = fmaxf(mx, __shfl_xor(mx, 16, 64));
      mx = fmaxf(mx, __shfl_xor(mx, 32, 64));

      if (__any(mx > m2 + 14.f)) {         // uniform defer-max rescale
        float mnew  = fmaxf(m2, mx);
        float alpha = __builtin_amdgcn_exp2f(m2 - mnew);
        m2 = mnew;
        lpart *= alpha;
#pragma unroll
        for (int df = 0; df < 8; df++) oacc[df] *= alpha;
      }

      // P = exp2(S - m), packed b64 writes into swizzled wave-private rows
      float rs = 0.f;
#pragma unroll
      for (int jf = 0; jf < 4; jf++) {
        bf16x4 pw;
#pragma unroll
        for (int r = 0; r < 4; r++) {
          float pe = __builtin_amdgcn_exp2f(sadj[jf][r] - m2);
          rs += pe;
          pw[r] = (bf16)pe;
        }
        *(bf16x4*)&P_lds[(wid * 16 + l16) * 64 + ((jf * 16 + l4 * 4) ^ swz)] = pw;
      }
      lpart += rs;

      // PV: O^T = mfma(Vt, P) -> D[col=l16=i][row=l4*4+r=d-sub]
#pragma unroll
      for (int kb2 = 0; kb2 < 2; ++kb2) {
        bf16x8 pf = *(const bf16x8*)&P_lds[(wid * 16 + l16) * 64 + ((kb2 * 32 + l4 * 8) ^ swz)];
#pragma unroll
        for (int df = 0; df < 8; df++) {
          bf16x8 vf = *(const bf16x8*)&V_[(df * 16 + l16) * 64 + ((kb2 * 32 + l4 * 8) ^ swz)];
          oacc[df] = __builtin_amdgcn_mfma_f32_16x16x32_bf16(vf, pf, oacc[df], 0, 0, 0);
        }
      }
    }

    // epilogue: finish l, normalize, silu-gate, vectorized 8B stores
    lpart += __shfl_xor(lpart, 16, 64);
    lpart += __shfl_xor(lpart, 32, 64);
    const float linv = 1.f / lpart;
    const bf16* pgrow = qkvp + (size_t)(b * SEQ + iq) * 8192 + 6144 + h * 128;
    bf16* grow = gated + (size_t)(b * SEQ + iq) * 2048 + h * 128;
#pragma unroll
    for (int df = 0; df < 8; df++) {
      const int d0 = df * 16 + l4 * 4;
      bf16x4 pg4 = *(const bf16x4*)(pgrow + d0);
      bf16x4 o4;
#pragma unroll
      for (int r = 0; r < 4; r++) {
        float o  = oacc[df][r] * linv;
        float pg = (float)pg4[r];
        float silu = pg / (1.f + __expf(-pg));
        o4[r] = (bf16)(silu * o);
      }
      *(bf16x4*)(grow + d0) = o4;
    }
  };

  run_strip(qp, qp + 1);
  __syncthreads();        // protect Kb[0]/Vb[0] before strip B's prologue stage
  run_strip(31 - qp, 32 - qp);
}

// ---------------------------------------------------------------------------
extern "C" void kernel_launch(void* const* d_in, const int* in_sizes, int n_in,
                              void* d_out, int out_size, void* d_ws, size_t ws_size,
                              hipStream_t stream) {
  (void)in_sizes; (void)n_in; (void)out_size; (void)ws_size;
  const float* x      = (const float*)d_in[0];
  const float* w_in   = (const float*)d_in[1];
  const float* w_out  = (const float*)d_in[2];
  const float* lnig   = (const float*)d_in[3];
  const float* lnib   = (const float*)d_in[4];
  const float* lnog   = (const float*)d_in[5];
  const float* lnob   = (const float*)d_in[6];
  const float* slopes = (const float*)d_in[7];
  const float* smf    = (const float*)d_in[8];
  float* out = (float*)d_out;

  char* ws = (char*)d_ws;
  size_t off = 0;
  bf16* hb      = (bf16*)(ws + off); off += (size_t)4096 * 1024 * 2;  // h (bf16)
  bf16* w_in_b  = (bf16*)(ws + off); off += (size_t)8192 * 1024 * 2;
  bf16* w_out_b = (bf16*)(ws + off); off += (size_t)1024 * 2048 * 2;
  bf16* qkvp    = (bf16*)(ws + off); off += (size_t)4096 * 8192 * 2;
  bf16* ksm     = (bf16*)(ws + off); off += (size_t)32 * 2048 * 128 * 2;
  bf16* gated   = (bf16*)(ws + off); off += (size_t)4096 * 2048 * 2;
  float* yb     = (float*)(ws + off); off += (size_t)4096 * 1024 * 4;
  bf16* vt      = (bf16*)yb;  // alias: vt dead before gemm2 writes yb

  cvt_kernel<<<4096, 256, 0, stream>>>(w_in,  w_in_b,  8388608 / 8);
  cvt_kernel<<<1024, 256, 0, stream>>>(w_out, w_out_b, 2097152 / 8);
  ln_kernel<true><<<4096, 256, 0, stream>>>(x, lnig, lnib, hb);
  gemm256<<<512, 512, 0, stream>>>(hb, w_in_b, qkvp, 4096, 8192, 1024, 4, 8, 8);
  smear_kernel<<<4096, 256, 0, stream>>>(qkvp, smf, ksm);
  vtrans_kernel<<<dim3(32, 32), 256, 0, stream>>>(qkvp, vt);
  attn_kernel<<<512, 256, 0, stream>>>(qkvp, ksm, vt, slopes, gated);
  gemm_bt<float><<<256, 256, 0, stream>>>(gated, w_out_b, yb, 4096, 1024, 2048, 1, 8, 4);
  ln_kernel<false><<<4096, 256, 0, stream>>>(yb, lnog, lnob, out);
}

// Round 8
// 236.136 us; speedup vs baseline: 1.7856x; 1.0225x over previous
//
#include <hip/hip_runtime.h>
#include <hip/hip_bf16.h>
#include <stdint.h>

// ---------------------------------------------------------------------------
// Block: LN -> [q,k,v,p] = h @ w_in^T -> key-smear -> causal attn w/ learned
// ALiBi -> o * silu(p) -> @ w_out^T -> LN.   B=2 L=2048 D=1024 H=16 Dh=128.
// Internal compute in bf16 MFMA.
// ---------------------------------------------------------------------------

typedef __bf16 bf16;
typedef bf16  bf16x8 __attribute__((ext_vector_type(8)));
typedef bf16  bf16x4 __attribute__((ext_vector_type(4)));
typedef float f32x4  __attribute__((ext_vector_type(4)));

#define SEQ   2048
#define NBATC 2

__device__ __forceinline__ void gld_lds16(const bf16* g, bf16* l) {
  __builtin_amdgcn_global_load_lds((const __attribute__((address_space(1))) void*)g,
                                   (__attribute__((address_space(3))) void*)l, 16, 0, 0);
}

// ---------------- f32 -> bf16 convert (8 elems/thread) ----------------------
__global__ __launch_bounds__(256) void cvt_kernel(const float* __restrict__ in,
                                                  bf16* __restrict__ out, int n8) {
  int t = blockIdx.x * 256 + threadIdx.x;
  if (t >= n8) return;
  const float4* p = (const float4*)in + (size_t)t * 2;
  float4 a = p[0], b = p[1];
  bf16x8 o;
  o[0] = (bf16)a.x; o[1] = (bf16)a.y; o[2] = (bf16)a.z; o[3] = (bf16)a.w;
  o[4] = (bf16)b.x; o[5] = (bf16)b.y; o[6] = (bf16)b.z; o[7] = (bf16)b.w;
  *((bf16x8*)out + t) = o;
}

// ---------------- LayerNorm over rows of 1024 f32 ---------------------------
template<bool BF16OUT>
__global__ __launch_bounds__(256) void ln_kernel(const float* __restrict__ x,
    const float* __restrict__ gamma, const float* __restrict__ beta,
    void* __restrict__ out) {
  const int row = blockIdx.x;
  const int tid = threadIdx.x;
  float4 v = *(const float4*)(x + (size_t)row * 1024 + tid * 4);
  float s  = v.x + v.y + v.z + v.w;
  float ss = v.x * v.x + v.y * v.y + v.z * v.z + v.w * v.w;
#pragma unroll
  for (int m = 1; m < 64; m <<= 1) { s += __shfl_xor(s, m, 64); ss += __shfl_xor(ss, m, 64); }
  __shared__ float red[8];
  if ((tid & 63) == 0) { red[tid >> 6] = s; red[(tid >> 6) + 4] = ss; }
  __syncthreads();
  s  = red[0] + red[1] + red[2] + red[3];
  ss = red[4] + red[5] + red[6] + red[7];
  const float mu  = s * (1.f / 1024.f);
  const float inv = rsqrtf(ss * (1.f / 1024.f) - mu * mu + 1e-5f);
  float4 g  = *(const float4*)(gamma + tid * 4);
  float4 bb = *(const float4*)(beta  + tid * 4);
  float y0 = (v.x - mu) * inv * g.x + bb.x;
  float y1 = (v.y - mu) * inv * g.y + bb.y;
  float y2 = (v.z - mu) * inv * g.z + bb.z;
  float y3 = (v.w - mu) * inv * g.w + bb.w;
  if (BF16OUT) {
    bf16* o = (bf16*)out + (size_t)row * 1024 + tid * 4;
    o[0] = (bf16)y0; o[1] = (bf16)y1; o[2] = (bf16)y2; o[3] = (bf16)y3;
  } else {
    float* o = (float*)out + (size_t)row * 1024 + tid * 4;
    o[0] = y0; o[1] = y1; o[2] = y2; o[3] = y3;
  }
}

// ---------------- fused key-smear (XOR-swizzled ksm) + V transpose ----------
// grid (kt 0..31, bh 0..31), 256 threads.
__global__ __launch_bounds__(256) void prep_kernel(const bf16* __restrict__ qkvp,
    const float* __restrict__ smf, bf16* __restrict__ ksm, bf16* __restrict__ vt) {
  __shared__ bf16 T[128][72];
  const int kt = blockIdx.x, bh = blockIdx.y;
  const int b = bh >> 4, h = bh & 15;
  const int t = threadIdx.x;

  // V tile -> LDS (transpose staging)
  {
    int i = t >> 2, d0 = (t & 3) * 32;
    const bf16* src = qkvp + (size_t)(b * SEQ + kt * 64 + i) * 8192 + 4096 + h * 128 + d0;
#pragma unroll
    for (int m = 0; m < 4; m++) {
      bf16x8 v8 = *(const bf16x8*)(src + m * 8);
#pragma unroll
      for (int e = 0; e < 8; e++) T[d0 + m * 8 + e][i] = v8[e];
    }
  }

  // key smear for this 64-row slice (global->global, swizzled store)
  {
    float sm = 1.f / (1.f + __expf(-smf[h]));
#pragma unroll
    for (int j = 0; j < 4; j++) {
      int c  = j * 256 + t;          // 1024 chunks of 8 elems
      int il = c >> 4, d8 = c & 15;
      int i  = kt * 64 + il;
      const bf16* base = qkvp + (size_t)(b * SEQ + i) * 8192 + 2048 + h * 128 + d8 * 8;
      bf16x8 cur = *(const bf16x8*)base;
      bf16x8 prv = cur;
      if (i > 0) prv = *(const bf16x8*)(base - 8192);
      bf16x8 o;
#pragma unroll
      for (int e = 0; e < 8; e++) {
        float pv = (i > 0) ? (float)prv[e] : 0.f;
        o[e] = (bf16)((1.f - sm) * (float)cur[e] + sm * pv);
      }
      size_t idx = ((size_t)bh * SEQ + i) * 128 + ((d8 * 8) ^ ((i & 7) << 3));
      *(bf16x8*)(ksm + idx) = o;
    }
  }

  __syncthreads();
  // write V^T tile, XOR-swizzled
  {
    int d = t >> 1, i0 = (t & 1) * 32;
    bf16* dst = vt + (size_t)bh * (SEQ * 128) + (size_t)kt * 8192 + d * 64;
#pragma unroll
    for (int m = 0; m < 4; m++) {
      bf16x8 v8 = *(const bf16x8*)&T[d][i0 + m * 8];
      *(bf16x8*)(dst + (((i0 + m * 8)) ^ ((d & 7) << 3))) = v8;
    }
  }
}

// ---------------- GEMM 256x256 tile, BK=64, counted-vmcnt pipeline ----------
__global__ __launch_bounds__(512) void gemm256(const bf16* __restrict__ A,
    const bf16* __restrict__ Bt, bf16* __restrict__ C, int M, int N, int K,
    int RX, int SX, int SY) {
  __shared__ bf16 As[2][256 * 64];
  __shared__ bf16 Bs[2][256 * 64];
  const int w   = blockIdx.x;
  const int xcd = w & 7, idx = w >> 3;
  const int rx = xcd % RX, ry = xcd / RX;
  const int bx = rx * SX + idx % SX;
  const int by = ry * SY + idx / SX;
  const int tid  = threadIdx.x;
  const int lane = tid & 63, wid = tid >> 6;
  const int l4 = lane >> 4, l16 = lane & 15;
  const int wr = wid >> 2, wc = wid & 3;          // 2 x 4 waves
  const int rowBase = by * 256, colBase = bx * 256;
  const int NT = K >> 6;

  f32x4 acc[8][4];
  const f32x4 z = {0.f, 0.f, 0.f, 0.f};
#pragma unroll
  for (int i = 0; i < 8; i++)
#pragma unroll
    for (int j = 0; j < 4; j++) acc[i][j] = z;

  auto stage = [&](int kt, int bsel) {
    const int k0 = kt * 64;
    bf16* ad = &As[bsel][tid * 8];
    bf16* bd = &Bs[bsel][tid * 8];
#pragma unroll
    for (int j = 0; j < 4; ++j) {
      const int c   = j * 512 + tid;       // 16-B chunk index (2048 total)
      const int row = c >> 3;              // 0..255
      const int sc  = ((c & 7) * 8) ^ ((row & 7) << 3);   // pre-swizzled src col
      gld_lds16(A  + (size_t)(rowBase + row) * K + k0 + sc, ad + j * 4096);
      gld_lds16(Bt + (size_t)(colBase + row) * K + k0 + sc, bd + j * 4096);
    }
  };

  stage(0, 0);
  for (int t = 0; t < NT; ++t) {
    const int cur = t & 1;
    if (t + 1 < NT) {
      stage(t + 1, cur ^ 1);                                   // 8 loads in flight
      asm volatile("s_waitcnt vmcnt(8)" ::: "memory");         // tile t done only
    } else {
      asm volatile("s_waitcnt vmcnt(0)" ::: "memory");
    }
    asm volatile("s_barrier" ::: "memory");                    // raw: no drain
    const bf16* a_ = &As[cur][0];
    const bf16* b_ = &Bs[cur][0];
#pragma unroll
    for (int ks = 0; ks < 2; ++ks) {
      bf16x8 bfr[4];
#pragma unroll
      for (int ni = 0; ni < 4; ++ni) {
        const int br = wc * 64 + ni * 16 + l16;
        bfr[ni] = *(const bf16x8*)&b_[br * 64 + ((ks * 32 + l4 * 8) ^ ((br & 7) << 3))];
      }
#pragma unroll
      for (int mi = 0; mi < 8; ++mi) {
        const int ar = wr * 128 + mi * 16 + l16;
        bf16x8 af = *(const bf16x8*)&a_[ar * 64 + ((ks * 32 + l4 * 8) ^ ((ar & 7) << 3))];
#pragma unroll
        for (int ni = 0; ni < 4; ++ni)
          acc[mi][ni] = __builtin_amdgcn_mfma_f32_16x16x32_bf16(af, bfr[ni], acc[mi][ni], 0, 0, 0);
      }
    }
    asm volatile("s_waitcnt lgkmcnt(0)" ::: "memory");   // LDS reads done
    asm volatile("s_barrier" ::: "memory");              // before next overwrite
  }

#pragma unroll
  for (int mi = 0; mi < 8; ++mi)
#pragma unroll
    for (int ni = 0; ni < 4; ++ni) {
      int row = rowBase + wr * 128 + mi * 16 + l4 * 4;
      int col = colBase + wc * 64 + ni * 16 + l16;
#pragma unroll
      for (int r = 0; r < 4; ++r)
        C[(size_t)(row + r) * N + col] = (bf16)acc[mi][ni][r];
    }
}

// ---------------- GEMM: C[M][N] = A[M][K] * Bt[N][K]^T  (128² fallback) -----
template<typename OutT>
__global__ __launch_bounds__(256) void gemm_bt(const bf16* __restrict__ A,
    const bf16* __restrict__ Bt, OutT* __restrict__ C, int M, int N, int K,
    int RX, int SX, int SY) {
  __shared__ bf16 As[128 * 32];
  __shared__ bf16 Bs[128 * 32];
  const int w   = blockIdx.x;
  const int xcd = w & 7, idx = w >> 3;
  const int rx = xcd % RX, ry = xcd / RX;
  const int bx = rx * SX + idx % SX;
  const int by = ry * SY + idx / SX;
  const int tid  = threadIdx.x;
  const int lane = tid & 63, wid = tid >> 6;
  const int l4 = lane >> 4, l16 = lane & 15;
  const int wr = wid >> 1, wc = wid & 1;
  const int rowBase = by * 128, colBase = bx * 128;

  const bf16* gA = A  + (size_t)(rowBase + (tid >> 2)) * K + (tid & 3) * 8;
  const bf16* gB = Bt + (size_t)(colBase + (tid >> 2)) * K + (tid & 3) * 8;
  const size_t rowStep = (size_t)64 * K;

  f32x4 acc[4][4];
  const f32x4 z = {0.f, 0.f, 0.f, 0.f};
#pragma unroll
  for (int i = 0; i < 4; i++)
#pragma unroll
    for (int j = 0; j < 4; j++) acc[i][j] = z;

  for (int k0 = 0; k0 < K; k0 += 32) {
    __syncthreads();
    gld_lds16(gA + k0,           &As[tid * 8]);
    gld_lds16(gA + rowStep + k0, &As[2048 + tid * 8]);
    gld_lds16(gB + k0,           &Bs[tid * 8]);
    gld_lds16(gB + rowStep + k0, &Bs[2048 + tid * 8]);
    __syncthreads();
    bf16x8 af[4], bfr[4];
#pragma unroll
    for (int mi = 0; mi < 4; mi++)
      af[mi] = *(const bf16x8*)&As[(wr * 64 + mi * 16 + l16) * 32 + l4 * 8];
#pragma unroll
    for (int ni = 0; ni < 4; ni++)
      bfr[ni] = *(const bf16x8*)&Bs[(wc * 64 + ni * 16 + l16) * 32 + l4 * 8];
#pragma unroll
    for (int mi = 0; mi < 4; mi++)
#pragma unroll
      for (int ni = 0; ni < 4; ni++)
        acc[mi][ni] = __builtin_amdgcn_mfma_f32_16x16x32_bf16(af[mi], bfr[ni], acc[mi][ni], 0, 0, 0);
  }
#pragma unroll
  for (int mi = 0; mi < 4; mi++)
#pragma unroll
    for (int ni = 0; ni < 4; ni++) {
      int row = rowBase + wr * 64 + mi * 16 + l4 * 4;
      int col = colBase + wc * 64 + ni * 16 + l16;
#pragma unroll
      for (int r = 0; r < 4; r++)
        C[(size_t)(row + r) * N + col] = (OutT)acc[mi][ni][r];
    }
}

// ---------------- flash attention + ALiBi + causal + silu-gate --------------
// 8-wave blocks, 128 q-rows each: staging amortized 2x, 16 waves/CU.
// gemm256-style schedule: stage(t+1); vmcnt(4); barrier; QK+softmax+PV;
// lgkmcnt(0); barrier.  Swapped-QK^T (lane owns one q-row).
__global__ __launch_bounds__(512, 4) void attn_kernel(const bf16* __restrict__ qkvp,
    const bf16* __restrict__ ksm, const bf16* __restrict__ vt,
    const float* __restrict__ slopes, bf16* __restrict__ gated) {
  const int w     = blockIdx.x;              // 512 = 8 xcd * (4 bh * 16 qt)
  const int xcd   = w & 7, r0 = w >> 3;
  const int bh    = xcd * 4 + (r0 & 3);      // XCD owns 4 bh strips
  const int qtile = 15 - (r0 >> 2);          // long blocks dispatch first
  const int b   = bh >> 4, h = bh & 15;
  const int tid = threadIdx.x, wid = tid >> 6, lane = tid & 63;
  const int l4 = lane >> 4, l16 = lane & 15;
  const int swz = (l16 & 7) << 3;
  const float LOG2E = 1.44269504f;
  const float s2 = 0.08838834764831845f * LOG2E;   // (1/sqrt(128))*log2e
  const float slopeL = slopes[h] * LOG2E;

  __shared__ bf16 Kb[2][64 * 128];
  __shared__ bf16 Vb[2][64 * 128];
  __shared__ bf16 P_lds[128 * 64];  // [qrow(128)][k ^ ((qrow&7)<<3)], wave-priv

  const bf16* ksmB = ksm + (size_t)bh * SEQ * 128;
  const bf16* vtB  = vt  + (size_t)bh * SEQ * 128;

  auto stage = [&](int kt, int bsel) {
#pragma unroll
    for (int j = 0; j < 2; j++) {
      const int c = j * 512 + tid;           // 1024 chunks of 16B
      gld_lds16(ksmB + (size_t)kt * 8192 + c * 8, &Kb[bsel][c * 8]);
      gld_lds16(vtB  + (size_t)kt * 8192 + c * 8, &Vb[bsel][c * 8]);
    }
  };

  const int iq = qtile * 128 + wid * 16 + l16;   // this lane's q-row
  bf16x8 qf[4];
  {
    const bf16* qrow = qkvp + (size_t)(b * SEQ + iq) * 8192 + h * 128;
#pragma unroll
    for (int kb = 0; kb < 4; kb++) qf[kb] = *(const bf16x8*)(qrow + kb * 32 + l4 * 8);
  }
  f32x4 oacc[8];   // oacc[df][r] = O[iq][df*16 + l4*4 + r]
  const f32x4 z = {0.f, 0.f, 0.f, 0.f};
#pragma unroll
  for (int i = 0; i < 8; i++) oacc[i] = z;
  float m2 = -1e38f, lpart = 0.f;

  const int nt = 2 * qtile + 2;
  stage(0, 0);
  for (int t = 0; t < nt; ++t) {
    const int cur = t & 1;
    if (t + 1 < nt) {
      stage(t + 1, cur ^ 1);                                // 4 loads in flight
      asm volatile("s_waitcnt vmcnt(4)" ::: "memory");      // tile t landed
    } else {
      asm volatile("s_waitcnt vmcnt(0)" ::: "memory");
    }
    __builtin_amdgcn_sched_barrier(0);
    __builtin_amdgcn_s_barrier();                           // all waves see K/V
    const bf16* K_ = Kb[cur];
    const bf16* V_ = Vb[cur];

    // S^T = K Q^T per wave: sacc[jf][r] = S[iq][t*64 + l4*4 + jf*16 + r]
    f32x4 sacc[4];
#pragma unroll
    for (int jf = 0; jf < 4; jf++) {
      f32x4 a = z;
#pragma unroll
      for (int kb = 0; kb < 4; kb++) {
        bf16x8 kf = *(const bf16x8*)&K_[(jf * 16 + l16) * 128 + ((kb * 32 + l4 * 8) ^ swz)];
        a = __builtin_amdgcn_mfma_f32_16x16x32_bf16(kf, qf[kb], a, 0, 0, 0);
      }
      sacc[jf] = a;
    }

    // exp2-domain bias + causal mask on the two boundary tiles
    const bool diag = (t >= 2 * qtile);
    const int kbase = t * 64 + l4 * 4;
#pragma unroll
    for (int jf = 0; jf < 4; jf++) {
#pragma unroll
      for (int r = 0; r < 4; r++) {
        int j = kbase + jf * 16 + r;
        float v = fmaf(sacc[jf][r], s2, (float)j * slopeL);
        if (diag && j > iq) v = -1e38f;
        sacc[jf][r] = v;
      }
    }

    // row max: lane-local 15 + 2 shuffles
    float mx = sacc[0][0];
#pragma unroll
    for (int jf = 0; jf < 4; jf++)
#pragma unroll
      for (int r = 0; r < 4; r++) mx = fmaxf(mx, sacc[jf][r]);
    mx = fmaxf(mx, __shfl_xor(mx, 16, 64));
    mx = fmaxf(mx, __shfl_xor(mx, 32, 64));

    if (__any(mx > m2 + 14.f)) {         // uniform defer-max rescale
      float mnew  = fmaxf(m2, mx);
      float alpha = __builtin_amdgcn_exp2f(m2 - mnew);
      m2 = mnew;
      lpart *= alpha;
#pragma unroll
      for (int df = 0; df < 8; df++) oacc[df] *= alpha;
    }

    // P = exp2(S - m), packed b64 writes into swizzled wave-private rows
    float rs = 0.f;
#pragma unroll
    for (int jf = 0; jf < 4; jf++) {
      bf16x4 pw;
#pragma unroll
      for (int r = 0; r < 4; r++) {
        float pe = __builtin_amdgcn_exp2f(sacc[jf][r] - m2);
        rs += pe;
        pw[r] = (bf16)pe;
      }
      *(bf16x4*)&P_lds[(wid * 16 + l16) * 64 + ((jf * 16 + l4 * 4) ^ swz)] = pw;
    }
    lpart += rs;

    // PV: O^T = mfma(Vt, P)
#pragma unroll
    for (int kb2 = 0; kb2 < 2; ++kb2) {
      bf16x8 pf = *(const bf16x8*)&P_lds[(wid * 16 + l16) * 64 + ((kb2 * 32 + l4 * 8) ^ swz)];
#pragma unroll
      for (int df = 0; df < 8; df++) {
        bf16x8 vf = *(const bf16x8*)&V_[(df * 16 + l16) * 64 + ((kb2 * 32 + l4 * 8) ^ swz)];
        oacc[df] = __builtin_amdgcn_mfma_f32_16x16x32_bf16(vf, pf, oacc[df], 0, 0, 0);
      }
    }

    asm volatile("s_waitcnt lgkmcnt(0)" ::: "memory");  // LDS reads done
    __builtin_amdgcn_s_barrier();                       // before next overwrite
  }

  // epilogue: finish l, normalize, silu-gate, vectorized 8B stores
  lpart += __shfl_xor(lpart, 16, 64);
  lpart += __shfl_xor(lpart, 32, 64);
  const float linv = 1.f / lpart;
  const bf16* pgrow = qkvp + (size_t)(b * SEQ + iq) * 8192 + 6144 + h * 128;
  bf16* grow = gated + (size_t)(b * SEQ + iq) * 2048 + h * 128;
#pragma unroll
  for (int df = 0; df < 8; df++) {
    const int d0 = df * 16 + l4 * 4;
    bf16x4 pg4 = *(const bf16x4*)(pgrow + d0);
    bf16x4 o4;
#pragma unroll
    for (int r = 0; r < 4; r++) {
      float o  = oacc[df][r] * linv;
      float pg = (float)pg4[r];
      float silu = pg / (1.f + __expf(-pg));
      o4[r] = (bf16)(silu * o);
    }
    *(bf16x4*)(grow + d0) = o4;
  }
}

// ---------------------------------------------------------------------------
extern "C" void kernel_launch(void* const* d_in, const int* in_sizes, int n_in,
                              void* d_out, int out_size, void* d_ws, size_t ws_size,
                              hipStream_t stream) {
  (void)in_sizes; (void)n_in; (void)out_size; (void)ws_size;
  const float* x      = (const float*)d_in[0];
  const float* w_in   = (const float*)d_in[1];
  const float* w_out  = (const float*)d_in[2];
  const float* lnig   = (const float*)d_in[3];
  const float* lnib   = (const float*)d_in[4];
  const float* lnog   = (const float*)d_in[5];
  const float* lnob   = (const float*)d_in[6];
  const float* slopes = (const float*)d_in[7];
  const float* smf    = (const float*)d_in[8];
  float* out = (float*)d_out;

  char* ws = (char*)d_ws;
  size_t off = 0;
  bf16* hb      = (bf16*)(ws + off); off += (size_t)4096 * 1024 * 2;  // h (bf16)
  bf16* w_in_b  = (bf16*)(ws + off); off += (size_t)8192 * 1024 * 2;
  bf16* w_out_b = (bf16*)(ws + off); off += (size_t)1024 * 2048 * 2;
  bf16* qkvp    = (bf16*)(ws + off); off += (size_t)4096 * 8192 * 2;
  bf16* ksm     = (bf16*)(ws + off); off += (size_t)32 * 2048 * 128 * 2;
  bf16* gated   = (bf16*)(ws + off); off += (size_t)4096 * 2048 * 2;
  float* yb     = (float*)(ws + off); off += (size_t)4096 * 1024 * 4;
  bf16* vt      = (bf16*)yb;  // alias: vt dead before gemm2 writes yb

  cvt_kernel<<<4096, 256, 0, stream>>>(w_in,  w_in_b,  8388608 / 8);
  cvt_kernel<<<1024, 256, 0, stream>>>(w_out, w_out_b, 2097152 / 8);
  ln_kernel<true><<<4096, 256, 0, stream>>>(x, lnig, lnib, hb);
  gemm256<<<512, 512, 0, stream>>>(hb, w_in_b, qkvp, 4096, 8192, 1024, 4, 8, 8);
  prep_kernel<<<dim3(32, 32), 256, 0, stream>>>(qkvp, smf, ksm, vt);
  attn_kernel<<<512, 512, 0, stream>>>(qkvp, ksm, vt, slopes, gated);
  gemm_bt<float><<<256, 256, 0, stream>>>(gated, w_out_b, yb, 4096, 1024, 2048, 1, 8, 4);
  ln_kernel<false><<<4096, 256, 0, stream>>>(yb, lnog, lnob, out);
}

// Round 9
// 230.428 us; speedup vs baseline: 1.8298x; 1.0248x over previous
//
#include <hip/hip_runtime.h>
#include <hip/hip_bf16.h>
#include <stdint.h>

// ---------------------------------------------------------------------------
// Block: LN -> [q,k,v,p] = h @ w_in^T -> key-smear -> causal attn w/ learned
// ALiBi -> o * silu(p) -> @ w_out^T -> LN.   B=2 L=2048 D=1024 H=16 Dh=128.
// Internal compute in bf16 MFMA.
// ---------------------------------------------------------------------------

typedef __bf16 bf16;
typedef bf16  bf16x8 __attribute__((ext_vector_type(8)));
typedef bf16  bf16x4 __attribute__((ext_vector_type(4)));
typedef float f32x4  __attribute__((ext_vector_type(4)));

#define SEQ   2048
#define NBATC 2

__device__ __forceinline__ void gld_lds16(const bf16* g, bf16* l) {
  __builtin_amdgcn_global_load_lds((const __attribute__((address_space(1))) void*)g,
                                   (__attribute__((address_space(3))) void*)l, 16, 0, 0);
}

// ---------------- f32 -> bf16 convert (8 elems/thread) ----------------------
__global__ __launch_bounds__(256) void cvt_kernel(const float* __restrict__ in,
                                                  bf16* __restrict__ out, int n8) {
  int t = blockIdx.x * 256 + threadIdx.x;
  if (t >= n8) return;
  const float4* p = (const float4*)in + (size_t)t * 2;
  float4 a = p[0], b = p[1];
  bf16x8 o;
  o[0] = (bf16)a.x; o[1] = (bf16)a.y; o[2] = (bf16)a.z; o[3] = (bf16)a.w;
  o[4] = (bf16)b.x; o[5] = (bf16)b.y; o[6] = (bf16)b.z; o[7] = (bf16)b.w;
  *((bf16x8*)out + t) = o;
}

// ---------------- LayerNorm over rows of 1024 f32 ---------------------------
template<bool BF16OUT>
__global__ __launch_bounds__(256) void ln_kernel(const float* __restrict__ x,
    const float* __restrict__ gamma, const float* __restrict__ beta,
    void* __restrict__ out) {
  const int row = blockIdx.x;
  const int tid = threadIdx.x;
  float4 v = *(const float4*)(x + (size_t)row * 1024 + tid * 4);
  float s  = v.x + v.y + v.z + v.w;
  float ss = v.x * v.x + v.y * v.y + v.z * v.z + v.w * v.w;
#pragma unroll
  for (int m = 1; m < 64; m <<= 1) { s += __shfl_xor(s, m, 64); ss += __shfl_xor(ss, m, 64); }
  __shared__ float red[8];
  if ((tid & 63) == 0) { red[tid >> 6] = s; red[(tid >> 6) + 4] = ss; }
  __syncthreads();
  s  = red[0] + red[1] + red[2] + red[3];
  ss = red[4] + red[5] + red[6] + red[7];
  const float mu  = s * (1.f / 1024.f);
  const float inv = rsqrtf(ss * (1.f / 1024.f) - mu * mu + 1e-5f);
  float4 g  = *(const float4*)(gamma + tid * 4);
  float4 bb = *(const float4*)(beta  + tid * 4);
  float y0 = (v.x - mu) * inv * g.x + bb.x;
  float y1 = (v.y - mu) * inv * g.y + bb.y;
  float y2 = (v.z - mu) * inv * g.z + bb.z;
  float y3 = (v.w - mu) * inv * g.w + bb.w;
  if (BF16OUT) {
    bf16* o = (bf16*)out + (size_t)row * 1024 + tid * 4;
    o[0] = (bf16)y0; o[1] = (bf16)y1; o[2] = (bf16)y2; o[3] = (bf16)y3;
  } else {
    float* o = (float*)out + (size_t)row * 1024 + tid * 4;
    o[0] = y0; o[1] = y1; o[2] = y2; o[3] = y3;
  }
}

// ---------------- fused key-smear (XOR-swizzled ksm) + V transpose ----------
// grid (kt 0..31, bh 0..31), 256 threads.
__global__ __launch_bounds__(256) void prep_kernel(const bf16* __restrict__ qkvp,
    const float* __restrict__ smf, bf16* __restrict__ ksm, bf16* __restrict__ vt) {
  __shared__ bf16 T[128][72];
  const int kt = blockIdx.x, bh = blockIdx.y;
  const int b = bh >> 4, h = bh & 15;
  const int t = threadIdx.x;

  // V tile -> LDS (transpose staging)
  {
    int i = t >> 2, d0 = (t & 3) * 32;
    const bf16* src = qkvp + (size_t)(b * SEQ + kt * 64 + i) * 8192 + 4096 + h * 128 + d0;
#pragma unroll
    for (int m = 0; m < 4; m++) {
      bf16x8 v8 = *(const bf16x8*)(src + m * 8);
#pragma unroll
      for (int e = 0; e < 8; e++) T[d0 + m * 8 + e][i] = v8[e];
    }
  }

  // key smear for this 64-row slice (global->global, swizzled store)
  {
    float sm = 1.f / (1.f + __expf(-smf[h]));
#pragma unroll
    for (int j = 0; j < 4; j++) {
      int c  = j * 256 + t;          // 1024 chunks of 8 elems
      int il = c >> 4, d8 = c & 15;
      int i  = kt * 64 + il;
      const bf16* base = qkvp + (size_t)(b * SEQ + i) * 8192 + 2048 + h * 128 + d8 * 8;
      bf16x8 cur = *(const bf16x8*)base;
      bf16x8 prv = cur;
      if (i > 0) prv = *(const bf16x8*)(base - 8192);
      bf16x8 o;
#pragma unroll
      for (int e = 0; e < 8; e++) {
        float pv = (i > 0) ? (float)prv[e] : 0.f;
        o[e] = (bf16)((1.f - sm) * (float)cur[e] + sm * pv);
      }
      size_t idx = ((size_t)bh * SEQ + i) * 128 + ((d8 * 8) ^ ((i & 7) << 3));
      *(bf16x8*)(ksm + idx) = o;
    }
  }

  __syncthreads();
  // write V^T tile, XOR-swizzled
  {
    int d = t >> 1, i0 = (t & 1) * 32;
    bf16* dst = vt + (size_t)bh * (SEQ * 128) + (size_t)kt * 8192 + d * 64;
#pragma unroll
    for (int m = 0; m < 4; m++) {
      bf16x8 v8 = *(const bf16x8*)&T[d][i0 + m * 8];
      *(bf16x8*)(dst + (((i0 + m * 8)) ^ ((d & 7) << 3))) = v8;
    }
  }
}

// ---------------- GEMM 256x256 tile, BK=64, counted-vmcnt pipeline ----------
__global__ __launch_bounds__(512) void gemm256(const bf16* __restrict__ A,
    const bf16* __restrict__ Bt, bf16* __restrict__ C, int M, int N, int K,
    int RX, int SX, int SY) {
  __shared__ bf16 As[2][256 * 64];
  __shared__ bf16 Bs[2][256 * 64];
  const int w   = blockIdx.x;
  const int xcd = w & 7, idx = w >> 3;
  const int rx = xcd % RX, ry = xcd / RX;
  const int bx = rx * SX + idx % SX;
  const int by = ry * SY + idx / SX;
  const int tid  = threadIdx.x;
  const int lane = tid & 63, wid = tid >> 6;
  const int l4 = lane >> 4, l16 = lane & 15;
  const int wr = wid >> 2, wc = wid & 3;          // 2 x 4 waves
  const int rowBase = by * 256, colBase = bx * 256;
  const int NT = K >> 6;

  f32x4 acc[8][4];
  const f32x4 z = {0.f, 0.f, 0.f, 0.f};
#pragma unroll
  for (int i = 0; i < 8; i++)
#pragma unroll
    for (int j = 0; j < 4; j++) acc[i][j] = z;

  auto stage = [&](int kt, int bsel) {
    const int k0 = kt * 64;
    bf16* ad = &As[bsel][tid * 8];
    bf16* bd = &Bs[bsel][tid * 8];
#pragma unroll
    for (int j = 0; j < 4; ++j) {
      const int c   = j * 512 + tid;       // 16-B chunk index (2048 total)
      const int row = c >> 3;              // 0..255
      const int sc  = ((c & 7) * 8) ^ ((row & 7) << 3);   // pre-swizzled src col
      gld_lds16(A  + (size_t)(rowBase + row) * K + k0 + sc, ad + j * 4096);
      gld_lds16(Bt + (size_t)(colBase + row) * K + k0 + sc, bd + j * 4096);
    }
  };

  stage(0, 0);
  for (int t = 0; t < NT; ++t) {
    const int cur = t & 1;
    if (t + 1 < NT) {
      stage(t + 1, cur ^ 1);                                   // 8 loads in flight
      asm volatile("s_waitcnt vmcnt(8)" ::: "memory");         // tile t done only
    } else {
      asm volatile("s_waitcnt vmcnt(0)" ::: "memory");
    }
    asm volatile("s_barrier" ::: "memory");                    // raw: no drain
    const bf16* a_ = &As[cur][0];
    const bf16* b_ = &Bs[cur][0];
#pragma unroll
    for (int ks = 0; ks < 2; ++ks) {
      bf16x8 bfr[4];
#pragma unroll
      for (int ni = 0; ni < 4; ++ni) {
        const int br = wc * 64 + ni * 16 + l16;
        bfr[ni] = *(const bf16x8*)&b_[br * 64 + ((ks * 32 + l4 * 8) ^ ((br & 7) << 3))];
      }
#pragma unroll
      for (int mi = 0; mi < 8; ++mi) {
        const int ar = wr * 128 + mi * 16 + l16;
        bf16x8 af = *(const bf16x8*)&a_[ar * 64 + ((ks * 32 + l4 * 8) ^ ((ar & 7) << 3))];
#pragma unroll
        for (int ni = 0; ni < 4; ++ni)
          acc[mi][ni] = __builtin_amdgcn_mfma_f32_16x16x32_bf16(af, bfr[ni], acc[mi][ni], 0, 0, 0);
      }
    }
    asm volatile("s_waitcnt lgkmcnt(0)" ::: "memory");   // LDS reads done
    asm volatile("s_barrier" ::: "memory");              // before next overwrite
  }

#pragma unroll
  for (int mi = 0; mi < 8; ++mi)
#pragma unroll
    for (int ni = 0; ni < 4; ++ni) {
      int row = rowBase + wr * 128 + mi * 16 + l4 * 4;
      int col = colBase + wc * 64 + ni * 16 + l16;
#pragma unroll
      for (int r = 0; r < 4; ++r)
        C[(size_t)(row + r) * N + col] = (bf16)acc[mi][ni][r];
    }
}

// ---------------- GEMM: C[M][N] = A[M][K] * Bt[N][K]^T  (128² fallback) -----
template<typename OutT>
__global__ __launch_bounds__(256) void gemm_bt(const bf16* __restrict__ A,
    const bf16* __restrict__ Bt, OutT* __restrict__ C, int M, int N, int K,
    int RX, int SX, int SY) {
  __shared__ bf16 As[128 * 32];
  __shared__ bf16 Bs[128 * 32];
  const int w   = blockIdx.x;
  const int xcd = w & 7, idx = w >> 3;
  const int rx = xcd % RX, ry = xcd / RX;
  const int bx = rx * SX + idx % SX;
  const int by = ry * SY + idx / SX;
  const int tid  = threadIdx.x;
  const int lane = tid & 63, wid = tid >> 6;
  const int l4 = lane >> 4, l16 = lane & 15;
  const int wr = wid >> 1, wc = wid & 1;
  const int rowBase = by * 128, colBase = bx * 128;

  const bf16* gA = A  + (size_t)(rowBase + (tid >> 2)) * K + (tid & 3) * 8;
  const bf16* gB = Bt + (size_t)(colBase + (tid >> 2)) * K + (tid & 3) * 8;
  const size_t rowStep = (size_t)64 * K;

  f32x4 acc[4][4];
  const f32x4 z = {0.f, 0.f, 0.f, 0.f};
#pragma unroll
  for (int i = 0; i < 4; i++)
#pragma unroll
    for (int j = 0; j < 4; j++) acc[i][j] = z;

  for (int k0 = 0; k0 < K; k0 += 32) {
    __syncthreads();
    gld_lds16(gA + k0,           &As[tid * 8]);
    gld_lds16(gA + rowStep + k0, &As[2048 + tid * 8]);
    gld_lds16(gB + k0,           &Bs[tid * 8]);
    gld_lds16(gB + rowStep + k0, &Bs[2048 + tid * 8]);
    __syncthreads();
    bf16x8 af[4], bfr[4];
#pragma unroll
    for (int mi = 0; mi < 4; mi++)
      af[mi] = *(const bf16x8*)&As[(wr * 64 + mi * 16 + l16) * 32 + l4 * 8];
#pragma unroll
    for (int ni = 0; ni < 4; ni++)
      bfr[ni] = *(const bf16x8*)&Bs[(wc * 64 + ni * 16 + l16) * 32 + l4 * 8];
#pragma unroll
    for (int mi = 0; mi < 4; mi++)
#pragma unroll
      for (int ni = 0; ni < 4; ni++)
        acc[mi][ni] = __builtin_amdgcn_mfma_f32_16x16x32_bf16(af[mi], bfr[ni], acc[mi][ni], 0, 0, 0);
  }
#pragma unroll
  for (int mi = 0; mi < 4; mi++)
#pragma unroll
    for (int ni = 0; ni < 4; ni++) {
      int row = rowBase + wr * 64 + mi * 16 + l4 * 4;
      int col = colBase + wc * 64 + ni * 16 + l16;
#pragma unroll
      for (int r = 0; r < 4; r++)
        C[(size_t)(row + r) * N + col] = (OutT)acc[mi][ni][r];
    }
}

// ---------------- flash attention + ALiBi + causal + silu-gate --------------
// 256 blocks = 1/CU exactly.  Block = (bh, pair p): strips qt=15-p then qt=p,
// uniform 34 tile-iters.  4-buffer LDS ring, TWO tiles per barrier pair:
// stage(tp+2,tp+3); vmcnt(8); barrier; compute tp, tp+1; lgkmcnt; barrier.
// Swapped-QK^T (lane owns one q-row).
__global__ __launch_bounds__(512, 2) void attn_kernel(const bf16* __restrict__ qkvp,
    const bf16* __restrict__ ksm, const bf16* __restrict__ vt,
    const float* __restrict__ slopes, bf16* __restrict__ gated) {
  const int w   = blockIdx.x;              // 256 = 8 xcd * 4 bh * 8 pairs
  const int xcd = w & 7;
  const int bh  = xcd * 4 + ((w >> 3) & 3);
  const int pr  = w >> 5;                  // 0..7
  const int b   = bh >> 4, h = bh & 15;
  const int tid = threadIdx.x, wid = tid >> 6, lane = tid & 63;
  const int l4 = lane >> 4, l16 = lane & 15;
  const int swz = (l16 & 7) << 3;
  const float LOG2E = 1.44269504f;
  const float s2 = 0.08838834764831845f * LOG2E;   // (1/sqrt(128))*log2e
  const float slopeL = slopes[h] * LOG2E;

  __shared__ bf16 Kb[4][64 * 128];
  __shared__ bf16 Vb[4][64 * 128];
  __shared__ bf16 P_lds[128 * 64];  // [qrow(128)][k ^ ((qrow&7)<<3)], wave-priv

  const bf16* ksmB = ksm + (size_t)bh * SEQ * 128;
  const bf16* vtB  = vt  + (size_t)bh * SEQ * 128;

  auto stage = [&](int kt, int bsel) {     // 4 loads/thread
#pragma unroll
    for (int j = 0; j < 2; j++) {
      const int c = j * 512 + tid;         // 1024 chunks of 16B
      gld_lds16(ksmB + (size_t)kt * 8192 + c * 8, &Kb[bsel][c * 8]);
      gld_lds16(vtB  + (size_t)kt * 8192 + c * 8, &Vb[bsel][c * 8]);
    }
  };

  auto run_strip = [&](int qtile) {
    const int nt = 2 * qtile + 2;
    const int iq = qtile * 128 + wid * 16 + l16;   // this lane's q-row
    bf16x8 qf[4];
    {
      const bf16* qrow = qkvp + (size_t)(b * SEQ + iq) * 8192 + h * 128;
#pragma unroll
      for (int kb = 0; kb < 4; kb++) qf[kb] = *(const bf16x8*)(qrow + kb * 32 + l4 * 8);
    }
    f32x4 oacc[8];   // oacc[df][r] = O[iq][df*16 + l4*4 + r]
    const f32x4 z = {0.f, 0.f, 0.f, 0.f};
#pragma unroll
    for (int i = 0; i < 8; i++) oacc[i] = z;
    float m2 = -1e38f, lpart = 0.f;

    auto tile = [&](int t, const bf16* K_, const bf16* V_) {
      // S^T = K Q^T per wave: sacc[jf][r] = S[iq][t*64 + l4*4 + jf*16 + r]
      f32x4 sacc[4];
#pragma unroll
      for (int jf = 0; jf < 4; jf++) {
        f32x4 a = z;
#pragma unroll
        for (int kb = 0; kb < 4; kb++) {
          bf16x8 kf = *(const bf16x8*)&K_[(jf * 16 + l16) * 128 + ((kb * 32 + l4 * 8) ^ swz)];
          a = __builtin_amdgcn_mfma_f32_16x16x32_bf16(kf, qf[kb], a, 0, 0, 0);
        }
        sacc[jf] = a;
      }

      // exp2-domain bias + causal mask on the two boundary tiles
      const bool diag = (t >= 2 * qtile);
      const int kbase = t * 64 + l4 * 4;
#pragma unroll
      for (int jf = 0; jf < 4; jf++) {
#pragma unroll
        for (int r = 0; r < 4; r++) {
          int j = kbase + jf * 16 + r;
          float v = fmaf(sacc[jf][r], s2, (float)j * slopeL);
          if (diag && j > iq) v = -1e38f;
          sacc[jf][r] = v;
        }
      }

      // row max: lane-local 15 + 2 shuffles
      float mx = sacc[0][0];
#pragma unroll
      for (int jf = 0; jf < 4; jf++)
#pragma unroll
        for (int r = 0; r < 4; r++) mx = fmaxf(mx, sacc[jf][r]);
      mx = fmaxf(mx, __shfl_xor(mx, 16, 64));
      mx = fmaxf(mx, __shfl_xor(mx, 32, 64));

      if (__any(mx > m2 + 14.f)) {         // uniform defer-max rescale
        float mnew  = fmaxf(m2, mx);
        float alpha = __builtin_amdgcn_exp2f(m2 - mnew);
        m2 = mnew;
        lpart *= alpha;
#pragma unroll
        for (int df = 0; df < 8; df++) oacc[df] *= alpha;
      }

      // P = exp2(S - m), packed b64 writes into swizzled wave-private rows
      float rs = 0.f;
#pragma unroll
      for (int jf = 0; jf < 4; jf++) {
        bf16x4 pw;
#pragma unroll
        for (int r = 0; r < 4; r++) {
          float pe = __builtin_amdgcn_exp2f(sacc[jf][r] - m2);
          rs += pe;
          pw[r] = (bf16)pe;
        }
        *(bf16x4*)&P_lds[(wid * 16 + l16) * 64 + ((jf * 16 + l4 * 4) ^ swz)] = pw;
      }
      lpart += rs;

      // PV: O^T = mfma(Vt, P)
#pragma unroll
      for (int kb2 = 0; kb2 < 2; ++kb2) {
        bf16x8 pf = *(const bf16x8*)&P_lds[(wid * 16 + l16) * 64 + ((kb2 * 32 + l4 * 8) ^ swz)];
#pragma unroll
        for (int df = 0; df < 8; df++) {
          bf16x8 vf = *(const bf16x8*)&V_[(df * 16 + l16) * 64 + ((kb2 * 32 + l4 * 8) ^ swz)];
          oacc[df] = __builtin_amdgcn_mfma_f32_16x16x32_bf16(vf, pf, oacc[df], 0, 0, 0);
        }
      }
    };

    stage(0, 0);
    stage(1, 1);
    for (int tp = 0; tp < nt; tp += 2) {
      if (tp + 2 < nt) {
        stage(tp + 2, (tp + 2) & 3);
        stage(tp + 3, (tp + 3) & 3);
        asm volatile("s_waitcnt vmcnt(8)" ::: "memory");   // tp, tp+1 landed
      } else {
        asm volatile("s_waitcnt vmcnt(0)" ::: "memory");
      }
      __builtin_amdgcn_sched_barrier(0);
      __builtin_amdgcn_s_barrier();                        // all waves see K/V
      tile(tp,     Kb[tp & 3],       Vb[tp & 3]);
      tile(tp + 1, Kb[(tp + 1) & 3], Vb[(tp + 1) & 3]);
      asm volatile("s_waitcnt lgkmcnt(0)" ::: "memory");   // LDS reads done
      __builtin_amdgcn_s_barrier();                        // before overwrite
    }

    // epilogue: finish l, normalize, silu-gate, vectorized 8B stores
    lpart += __shfl_xor(lpart, 16, 64);
    lpart += __shfl_xor(lpart, 32, 64);
    const float linv = 1.f / lpart;
    const bf16* pgrow = qkvp + (size_t)(b * SEQ + iq) * 8192 + 6144 + h * 128;
    bf16* grow = gated + (size_t)(b * SEQ + iq) * 2048 + h * 128;
#pragma unroll
    for (int df = 0; df < 8; df++) {
      const int d0 = df * 16 + l4 * 4;
      bf16x4 pg4 = *(const bf16x4*)(pgrow + d0);
      bf16x4 o4;
#pragma unroll
      for (int r = 0; r < 4; r++) {
        float o  = oacc[df][r] * linv;
        float pg = (float)pg4[r];
        float silu = pg / (1.f + __expf(-pg));
        o4[r] = (bf16)(silu * o);
      }
      *(bf16x4*)(grow + d0) = o4;
    }
  };

  run_strip(15 - pr);    // long strip first
  run_strip(pr);         // short strip re-reads L2-warm K/V
}

// ---------------------------------------------------------------------------
extern "C" void kernel_launch(void* const* d_in, const int* in_sizes, int n_in,
                              void* d_out, int out_size, void* d_ws, size_t ws_size,
                              hipStream_t stream) {
  (void)in_sizes; (void)n_in; (void)out_size; (void)ws_size;
  const float* x      = (const float*)d_in[0];
  const float* w_in   = (const float*)d_in[1];
  const float* w_out  = (const float*)d_in[2];
  const float* lnig   = (const float*)d_in[3];
  const float* lnib   = (const float*)d_in[4];
  const float* lnog   = (const float*)d_in[5];
  const float* lnob   = (const float*)d_in[6];
  const float* slopes = (const float*)d_in[7];
  const float* smf    = (const float*)d_in[8];
  float* out = (float*)d_out;

  char* ws = (char*)d_ws;
  size_t off = 0;
  bf16* hb      = (bf16*)(ws + off); off += (size_t)4096 * 1024 * 2;  // h (bf16)
  bf16* w_in_b  = (bf16*)(ws + off); off += (size_t)8192 * 1024 * 2;
  bf16* w_out_b = (bf16*)(ws + off); off += (size_t)1024 * 2048 * 2;
  bf16* qkvp    = (bf16*)(ws + off); off += (size_t)4096 * 8192 * 2;
  bf16* ksm     = (bf16*)(ws + off); off += (size_t)32 * 2048 * 128 * 2;
  bf16* gated   = (bf16*)(ws + off); off += (size_t)4096 * 2048 * 2;
  float* yb     = (float*)(ws + off); off += (size_t)4096 * 1024 * 4;
  bf16* vt      = (bf16*)yb;  // alias: vt dead before gemm2 writes yb

  cvt_kernel<<<4096, 256, 0, stream>>>(w_in,  w_in_b,  8388608 / 8);
  cvt_kernel<<<1024, 256, 0, stream>>>(w_out, w_out_b, 2097152 / 8);
  ln_kernel<true><<<4096, 256, 0, stream>>>(x, lnig, lnib, hb);
  gemm256<<<512, 512, 0, stream>>>(hb, w_in_b, qkvp, 4096, 8192, 1024, 4, 8, 8);
  prep_kernel<<<dim3(32, 32), 256, 0, stream>>>(qkvp, smf, ksm, vt);
  attn_kernel<<<256, 512, 0, stream>>>(qkvp, ksm, vt, slopes, gated);
  gemm_bt<float><<<256, 256, 0, stream>>>(gated, w_out_b, yb, 4096, 1024, 2048, 1, 8, 4);
  ln_kernel<false><<<4096, 256, 0, stream>>>(yb, lnog, lnob, out);
}

// Round 10
// 229.090 us; speedup vs baseline: 1.8405x; 1.0058x over previous
//
#include <hip/hip_runtime.h>
#include <hip/hip_bf16.h>
#include <stdint.h>

// ---------------------------------------------------------------------------
// Block: LN -> [q,k,v,p] = h @ w_in^T -> key-smear -> causal attn w/ learned
// ALiBi -> o * silu(p) -> @ w_out^T -> LN.   B=2 L=2048 D=1024 H=16 Dh=128.
// Internal compute in bf16 MFMA.
// ---------------------------------------------------------------------------

typedef __bf16 bf16;
typedef bf16  bf16x8 __attribute__((ext_vector_type(8)));
typedef bf16  bf16x4 __attribute__((ext_vector_type(4)));
typedef float f32x4  __attribute__((ext_vector_type(4)));

#define SEQ   2048
#define NBATC 2

__device__ __forceinline__ void gld_lds16(const bf16* g, bf16* l) {
  __builtin_amdgcn_global_load_lds((const __attribute__((address_space(1))) void*)g,
                                   (__attribute__((address_space(3))) void*)l, 16, 0, 0);
}

// ---------------- f32 -> bf16 convert (8 elems/thread) ----------------------
__global__ __launch_bounds__(256) void cvt_kernel(const float* __restrict__ in,
                                                  bf16* __restrict__ out, int n8) {
  int t = blockIdx.x * 256 + threadIdx.x;
  if (t >= n8) return;
  const float4* p = (const float4*)in + (size_t)t * 2;
  float4 a = p[0], b = p[1];
  bf16x8 o;
  o[0] = (bf16)a.x; o[1] = (bf16)a.y; o[2] = (bf16)a.z; o[3] = (bf16)a.w;
  o[4] = (bf16)b.x; o[5] = (bf16)b.y; o[6] = (bf16)b.z; o[7] = (bf16)b.w;
  *((bf16x8*)out + t) = o;
}

// ---------------- LayerNorm over rows of 1024 f32 ---------------------------
template<bool BF16OUT>
__global__ __launch_bounds__(256) void ln_kernel(const float* __restrict__ x,
    const float* __restrict__ gamma, const float* __restrict__ beta,
    void* __restrict__ out) {
  const int row = blockIdx.x;
  const int tid = threadIdx.x;
  float4 v = *(const float4*)(x + (size_t)row * 1024 + tid * 4);
  float s  = v.x + v.y + v.z + v.w;
  float ss = v.x * v.x + v.y * v.y + v.z * v.z + v.w * v.w;
#pragma unroll
  for (int m = 1; m < 64; m <<= 1) { s += __shfl_xor(s, m, 64); ss += __shfl_xor(ss, m, 64); }
  __shared__ float red[8];
  if ((tid & 63) == 0) { red[tid >> 6] = s; red[(tid >> 6) + 4] = ss; }
  __syncthreads();
  s  = red[0] + red[1] + red[2] + red[3];
  ss = red[4] + red[5] + red[6] + red[7];
  const float mu  = s * (1.f / 1024.f);
  const float inv = rsqrtf(ss * (1.f / 1024.f) - mu * mu + 1e-5f);
  float4 g  = *(const float4*)(gamma + tid * 4);
  float4 bb = *(const float4*)(beta  + tid * 4);
  float y0 = (v.x - mu) * inv * g.x + bb.x;
  float y1 = (v.y - mu) * inv * g.y + bb.y;
  float y2 = (v.z - mu) * inv * g.z + bb.z;
  float y3 = (v.w - mu) * inv * g.w + bb.w;
  if (BF16OUT) {
    bf16* o = (bf16*)out + (size_t)row * 1024 + tid * 4;
    o[0] = (bf16)y0; o[1] = (bf16)y1; o[2] = (bf16)y2; o[3] = (bf16)y3;
  } else {
    float* o = (float*)out + (size_t)row * 1024 + tid * 4;
    o[0] = y0; o[1] = y1; o[2] = y2; o[3] = y3;
  }
}

// ---------------- fused key-smear (XOR-swizzled ksm) + V transpose ----------
// grid (kt 0..31, bh 0..31), 256 threads.
__global__ __launch_bounds__(256) void prep_kernel(const bf16* __restrict__ qkvp,
    const float* __restrict__ smf, bf16* __restrict__ ksm, bf16* __restrict__ vt) {
  __shared__ bf16 T[128][72];
  const int kt = blockIdx.x, bh = blockIdx.y;
  const int b = bh >> 4, h = bh & 15;
  const int t = threadIdx.x;

  // V tile -> LDS (transpose staging)
  {
    int i = t >> 2, d0 = (t & 3) * 32;
    const bf16* src = qkvp + (size_t)(b * SEQ + kt * 64 + i) * 8192 + 4096 + h * 128 + d0;
#pragma unroll
    for (int m = 0; m < 4; m++) {
      bf16x8 v8 = *(const bf16x8*)(src + m * 8);
#pragma unroll
      for (int e = 0; e < 8; e++) T[d0 + m * 8 + e][i] = v8[e];
    }
  }

  // key smear for this 64-row slice (global->global, swizzled store)
  {
    float sm = 1.f / (1.f + __expf(-smf[h]));
#pragma unroll
    for (int j = 0; j < 4; j++) {
      int c  = j * 256 + t;          // 1024 chunks of 8 elems
      int il = c >> 4, d8 = c & 15;
      int i  = kt * 64 + il;
      const bf16* base = qkvp + (size_t)(b * SEQ + i) * 8192 + 2048 + h * 128 + d8 * 8;
      bf16x8 cur = *(const bf16x8*)base;
      bf16x8 prv = cur;
      if (i > 0) prv = *(const bf16x8*)(base - 8192);
      bf16x8 o;
#pragma unroll
      for (int e = 0; e < 8; e++) {
        float pv = (i > 0) ? (float)prv[e] : 0.f;
        o[e] = (bf16)((1.f - sm) * (float)cur[e] + sm * pv);
      }
      size_t idx = ((size_t)bh * SEQ + i) * 128 + ((d8 * 8) ^ ((i & 7) << 3));
      *(bf16x8*)(ksm + idx) = o;
    }
  }

  __syncthreads();
  // write V^T tile, XOR-swizzled
  {
    int d = t >> 1, i0 = (t & 1) * 32;
    bf16* dst = vt + (size_t)bh * (SEQ * 128) + (size_t)kt * 8192 + d * 64;
#pragma unroll
    for (int m = 0; m < 4; m++) {
      bf16x8 v8 = *(const bf16x8*)&T[d][i0 + m * 8];
      *(bf16x8*)(dst + (((i0 + m * 8)) ^ ((d & 7) << 3))) = v8;
    }
  }
}

// ---------------- GEMM 256x256 tile, BK=64, 4-phase interleaved pipeline ----
// 8 waves (2M x 4N), 512 threads.  Per K-tile: 4 phases p=(ks=p>>1, mh=p&1):
// {4 A-frag ds_read (+4 B-frag on mh==0); stage 2 half-tiles of t+1 at p=0/1;
//  barrier; lgkmcnt(0)+sched_barrier; setprio(1); 16 MFMA; setprio(0);
//  [p==3: vmcnt(0) ~3 phases after issue]; barrier}.  Full dbuf (reads buf,
// stages buf^1).  LDS XOR-swizzle via pre-swizzled global source (involution).
__global__ __launch_bounds__(512, 2) void gemm256(const bf16* __restrict__ A,
    const bf16* __restrict__ Bt, bf16* __restrict__ C, int M, int N, int K,
    int RX, int SX, int SY) {
  __shared__ bf16 As[2][2][128 * 64];   // [buf][half][row*64 + swizzled col]
  __shared__ bf16 Bs[2][2][128 * 64];
  const int w   = blockIdx.x;
  const int xcd = w & 7, idx = w >> 3;
  const int rx = xcd % RX, ry = xcd / RX;
  const int bx = rx * SX + idx % SX;
  const int by = ry * SY + idx / SX;
  const int tid  = threadIdx.x;
  const int lane = tid & 63, wid = tid >> 6;
  const int l4 = lane >> 4, l16 = lane & 15;
  const int wr = wid >> 2, wc = wid & 3;          // 2 x 4 waves
  const int rowBase = by * 256, colBase = bx * 256;
  const int NT = K >> 6;

  f32x4 acc[8][4];
  const f32x4 z = {0.f, 0.f, 0.f, 0.f};
#pragma unroll
  for (int i = 0; i < 8; i++)
#pragma unroll
    for (int j = 0; j < 4; j++) acc[i][j] = z;

  // hp=0: A half-tiles (rows half*128..+128); hp=1: B half-tiles.
  auto stage_pair = [&](int t_, int hp) {
    const int buf = t_ & 1, k0 = t_ * 64;
#pragma unroll
    for (int half = 0; half < 2; ++half) {
      const bf16* src = (hp == 0) ? (A  + (size_t)(rowBase + half * 128) * K)
                                  : (Bt + (size_t)(colBase + half * 128) * K);
      bf16* dst = (hp == 0) ? &As[buf][half][0] : &Bs[buf][half][0];
#pragma unroll
      for (int j = 0; j < 2; ++j) {
        const int c   = j * 512 + tid;    // 1024 chunks of 16B per half-tile
        const int row = c >> 3;           // 0..127
        const int sc  = ((c & 7) * 8) ^ ((row & 7) << 3);
        gld_lds16(src + (size_t)row * K + k0 + sc, dst + c * 8);
      }
    }
  };

  stage_pair(0, 0);
  stage_pair(0, 1);
  asm volatile("s_waitcnt vmcnt(0)" ::: "memory");
  __builtin_amdgcn_sched_barrier(0);
  __builtin_amdgcn_s_barrier();

  for (int t = 0; t < NT; ++t) {
    const int buf = t & 1;
    const bf16* aH = &As[buf][wr][0];
    const bf16* bH = &Bs[buf][wc >> 1][0];
    bf16x8 bfr[4];
#pragma unroll
    for (int p = 0; p < 4; ++p) {
      const int ks = p >> 1, mh = p & 1;
      // A fragments for this phase (4 x ds_read_b128)
      bf16x8 af[4];
#pragma unroll
      for (int q = 0; q < 4; ++q) {
        const int lr = mh * 64 + q * 16 + l16;
        af[q] = *(const bf16x8*)&aH[lr * 64 + ((ks * 32 + l4 * 8) ^ ((lr & 7) << 3))];
      }
      if (mh == 0) {   // B fragments for this ks (4 x ds_read_b128), reused at mh==1
#pragma unroll
        for (int ni = 0; ni < 4; ++ni) {
          const int lr = (wc & 1) * 64 + ni * 16 + l16;
          bfr[ni] = *(const bf16x8*)&bH[lr * 64 + ((ks * 32 + l4 * 8) ^ ((lr & 7) << 3))];
        }
      }
      if (p == 0 && t + 1 < NT) stage_pair(t + 1, 0);   // A halves of next tile
      if (p == 1 && t + 1 < NT) stage_pair(t + 1, 1);   // B halves of next tile
      __builtin_amdgcn_s_barrier();
      asm volatile("s_waitcnt lgkmcnt(0)" ::: "memory");
      __builtin_amdgcn_sched_barrier(0);
      __builtin_amdgcn_s_setprio(1);
#pragma unroll
      for (int q = 0; q < 4; ++q)
#pragma unroll
        for (int ni = 0; ni < 4; ++ni)
          acc[mh * 4 + q][ni] =
              __builtin_amdgcn_mfma_f32_16x16x32_bf16(af[q], bfr[ni], acc[mh * 4 + q][ni], 0, 0, 0);
      __builtin_amdgcn_s_setprio(0);
      if (p == 3) {   // next tile's loads issued ~3 phases ago -> near-free
        asm volatile("s_waitcnt vmcnt(0)" ::: "memory");
        __builtin_amdgcn_sched_barrier(0);
      }
      __builtin_amdgcn_s_barrier();
    }
  }

#pragma unroll
  for (int mi = 0; mi < 8; ++mi)
#pragma unroll
    for (int ni = 0; ni < 4; ++ni) {
      int row = rowBase + wr * 128 + mi * 16 + l4 * 4;
      int col = colBase + wc * 64 + ni * 16 + l16;
#pragma unroll
      for (int r = 0; r < 4; ++r)
        C[(size_t)(row + r) * N + col] = (bf16)acc[mi][ni][r];
    }
}

// ---------------- GEMM: C[M][N] = A[M][K] * Bt[N][K]^T  (128² fallback) -----
template<typename OutT>
__global__ __launch_bounds__(256) void gemm_bt(const bf16* __restrict__ A,
    const bf16* __restrict__ Bt, OutT* __restrict__ C, int M, int N, int K,
    int RX, int SX, int SY) {
  __shared__ bf16 As[128 * 32];
  __shared__ bf16 Bs[128 * 32];
  const int w   = blockIdx.x;
  const int xcd = w & 7, idx = w >> 3;
  const int rx = xcd % RX, ry = xcd / RX;
  const int bx = rx * SX + idx % SX;
  const int by = ry * SY + idx / SX;
  const int tid  = threadIdx.x;
  const int lane = tid & 63, wid = tid >> 6;
  const int l4 = lane >> 4, l16 = lane & 15;
  const int wr = wid >> 1, wc = wid & 1;
  const int rowBase = by * 128, colBase = bx * 128;

  const bf16* gA = A  + (size_t)(rowBase + (tid >> 2)) * K + (tid & 3) * 8;
  const bf16* gB = Bt + (size_t)(colBase + (tid >> 2)) * K + (tid & 3) * 8;
  const size_t rowStep = (size_t)64 * K;

  f32x4 acc[4][4];
  const f32x4 z = {0.f, 0.f, 0.f, 0.f};
#pragma unroll
  for (int i = 0; i < 4; i++)
#pragma unroll
    for (int j = 0; j < 4; j++) acc[i][j] = z;

  for (int k0 = 0; k0 < K; k0 += 32) {
    __syncthreads();
    gld_lds16(gA + k0,           &As[tid * 8]);
    gld_lds16(gA + rowStep + k0, &As[2048 + tid * 8]);
    gld_lds16(gB + k0,           &Bs[tid * 8]);
    gld_lds16(gB + rowStep + k0, &Bs[2048 + tid * 8]);
    __syncthreads();
    bf16x8 af[4], bfr[4];
#pragma unroll
    for (int mi = 0; mi < 4; mi++)
      af[mi] = *(const bf16x8*)&As[(wr * 64 + mi * 16 + l16) * 32 + l4 * 8];
#pragma unroll
    for (int ni = 0; ni < 4; ni++)
      bfr[ni] = *(const bf16x8*)&Bs[(wc * 64 + ni * 16 + l16) * 32 + l4 * 8];
#pragma unroll
    for (int mi = 0; mi < 4; mi++)
#pragma unroll
      for (int ni = 0; ni < 4; ni++)
        acc[mi][ni] = __builtin_amdgcn_mfma_f32_16x16x32_bf16(af[mi], bfr[ni], acc[mi][ni], 0, 0, 0);
  }
#pragma unroll
  for (int mi = 0; mi < 4; mi++)
#pragma unroll
    for (int ni = 0; ni < 4; ni++) {
      int row = rowBase + wr * 64 + mi * 16 + l4 * 4;
      int col = colBase + wc * 64 + ni * 16 + l16;
#pragma unroll
      for (int r = 0; r < 4; r++)
        C[(size_t)(row + r) * N + col] = (OutT)acc[mi][ni][r];
    }
}

// ---------------- flash attention + ALiBi + causal + silu-gate --------------
// 256 blocks = 1/CU exactly.  Block = (bh, pair p): strips qt=15-p then qt=p,
// uniform 34 tile-iters.  4-buffer LDS ring, TWO tiles per barrier pair:
// stage(tp+2,tp+3); vmcnt(8); barrier; compute tp, tp+1; lgkmcnt; barrier.
// Swapped-QK^T (lane owns one q-row).
__global__ __launch_bounds__(512, 2) void attn_kernel(const bf16* __restrict__ qkvp,
    const bf16* __restrict__ ksm, const bf16* __restrict__ vt,
    const float* __restrict__ slopes, bf16* __restrict__ gated) {
  const int w   = blockIdx.x;              // 256 = 8 xcd * 4 bh * 8 pairs
  const int xcd = w & 7;
  const int bh  = xcd * 4 + ((w >> 3) & 3);
  const int pr  = w >> 5;                  // 0..7
  const int b   = bh >> 4, h = bh & 15;
  const int tid = threadIdx.x, wid = tid >> 6, lane = tid & 63;
  const int l4 = lane >> 4, l16 = lane & 15;
  const int swz = (l16 & 7) << 3;
  const float LOG2E = 1.44269504f;
  const float s2 = 0.08838834764831845f * LOG2E;   // (1/sqrt(128))*log2e
  const float slopeL = slopes[h] * LOG2E;

  __shared__ bf16 Kb[4][64 * 128];
  __shared__ bf16 Vb[4][64 * 128];
  __shared__ bf16 P_lds[128 * 64];  // [qrow(128)][k ^ ((qrow&7)<<3)], wave-priv

  const bf16* ksmB = ksm + (size_t)bh * SEQ * 128;
  const bf16* vtB  = vt  + (size_t)bh * SEQ * 128;

  auto stage = [&](int kt, int bsel) {     // 4 loads/thread
#pragma unroll
    for (int j = 0; j < 2; j++) {
      const int c = j * 512 + tid;         // 1024 chunks of 16B
      gld_lds16(ksmB + (size_t)kt * 8192 + c * 8, &Kb[bsel][c * 8]);
      gld_lds16(vtB  + (size_t)kt * 8192 + c * 8, &Vb[bsel][c * 8]);
    }
  };

  auto run_strip = [&](int qtile) {
    const int nt = 2 * qtile + 2;
    const int iq = qtile * 128 + wid * 16 + l16;   // this lane's q-row
    bf16x8 qf[4];
    {
      const bf16* qrow = qkvp + (size_t)(b * SEQ + iq) * 8192 + h * 128;
#pragma unroll
      for (int kb = 0; kb < 4; kb++) qf[kb] = *(const bf16x8*)(qrow + kb * 32 + l4 * 8);
    }
    f32x4 oacc[8];   // oacc[df][r] = O[iq][df*16 + l4*4 + r]
    const f32x4 z = {0.f, 0.f, 0.f, 0.f};
#pragma unroll
    for (int i = 0; i < 8; i++) oacc[i] = z;
    float m2 = -1e38f, lpart = 0.f;

    auto tile = [&](int t, const bf16* K_, const bf16* V_) {
      // S^T = K Q^T per wave: sacc[jf][r] = S[iq][t*64 + l4*4 + jf*16 + r]
      f32x4 sacc[4];
#pragma unroll
      for (int jf = 0; jf < 4; jf++) {
        f32x4 a = z;
#pragma unroll
        for (int kb = 0; kb < 4; kb++) {
          bf16x8 kf = *(const bf16x8*)&K_[(jf * 16 + l16) * 128 + ((kb * 32 + l4 * 8) ^ swz)];
          a = __builtin_amdgcn_mfma_f32_16x16x32_bf16(kf, qf[kb], a, 0, 0, 0);
        }
        sacc[jf] = a;
      }

      // exp2-domain bias + causal mask on the two boundary tiles
      const bool diag = (t >= 2 * qtile);
      const int kbase = t * 64 + l4 * 4;
#pragma unroll
      for (int jf = 0; jf < 4; jf++) {
#pragma unroll
        for (int r = 0; r < 4; r++) {
          int j = kbase + jf * 16 + r;
          float v = fmaf(sacc[jf][r], s2, (float)j * slopeL);
          if (diag && j > iq) v = -1e38f;
          sacc[jf][r] = v;
        }
      }

      // row max: lane-local 15 + 2 shuffles
      float mx = sacc[0][0];
#pragma unroll
      for (int jf = 0; jf < 4; jf++)
#pragma unroll
        for (int r = 0; r < 4; r++) mx = fmaxf(mx, sacc[jf][r]);
      mx = fmaxf(mx, __shfl_xor(mx, 16, 64));
      mx = fmaxf(mx, __shfl_xor(mx, 32, 64));

      if (__any(mx > m2 + 14.f)) {         // uniform defer-max rescale
        float mnew  = fmaxf(m2, mx);
        float alpha = __builtin_amdgcn_exp2f(m2 - mnew);
        m2 = mnew;
        lpart *= alpha;
#pragma unroll
        for (int df = 0; df < 8; df++) oacc[df] *= alpha;
      }

      // P = exp2(S - m), packed b64 writes into swizzled wave-private rows
      float rs = 0.f;
#pragma unroll
      for (int jf = 0; jf < 4; jf++) {
        bf16x4 pw;
#pragma unroll
        for (int r = 0; r < 4; r++) {
          float pe = __builtin_amdgcn_exp2f(sacc[jf][r] - m2);
          rs += pe;
          pw[r] = (bf16)pe;
        }
        *(bf16x4*)&P_lds[(wid * 16 + l16) * 64 + ((jf * 16 + l4 * 4) ^ swz)] = pw;
      }
      lpart += rs;

      // PV: O^T = mfma(Vt, P)
#pragma unroll
      for (int kb2 = 0; kb2 < 2; ++kb2) {
        bf16x8 pf = *(const bf16x8*)&P_lds[(wid * 16 + l16) * 64 + ((kb2 * 32 + l4 * 8) ^ swz)];
#pragma unroll
        for (int df = 0; df < 8; df++) {
          bf16x8 vf = *(const bf16x8*)&V_[(df * 16 + l16) * 64 + ((kb2 * 32 + l4 * 8) ^ swz)];
          oacc[df] = __builtin_amdgcn_mfma_f32_16x16x32_bf16(vf, pf, oacc[df], 0, 0, 0);
        }
      }
    };

    stage(0, 0);
    stage(1, 1);
    for (int tp = 0; tp < nt; tp += 2) {
      if (tp + 2 < nt) {
        stage(tp + 2, (tp + 2) & 3);
        stage(tp + 3, (tp + 3) & 3);
        asm volatile("s_waitcnt vmcnt(8)" ::: "memory");   // tp, tp+1 landed
      } else {
        asm volatile("s_waitcnt vmcnt(0)" ::: "memory");
      }
      __builtin_amdgcn_sched_barrier(0);
      __builtin_amdgcn_s_barrier();                        // all waves see K/V
      tile(tp,     Kb[tp & 3],       Vb[tp & 3]);
      tile(tp + 1, Kb[(tp + 1) & 3], Vb[(tp + 1) & 3]);
      asm volatile("s_waitcnt lgkmcnt(0)" ::: "memory");   // LDS reads done
      __builtin_amdgcn_s_barrier();                        // before overwrite
    }

    // epilogue: finish l, normalize, silu-gate, vectorized 8B stores
    lpart += __shfl_xor(lpart, 16, 64);
    lpart += __shfl_xor(lpart, 32, 64);
    const float linv = 1.f / lpart;
    const bf16* pgrow = qkvp + (size_t)(b * SEQ + iq) * 8192 + 6144 + h * 128;
    bf16* grow = gated + (size_t)(b * SEQ + iq) * 2048 + h * 128;
#pragma unroll
    for (int df = 0; df < 8; df++) {
      const int d0 = df * 16 + l4 * 4;
      bf16x4 pg4 = *(const bf16x4*)(pgrow + d0);
      bf16x4 o4;
#pragma unroll
      for (int r = 0; r < 4; r++) {
        float o  = oacc[df][r] * linv;
        float pg = (float)pg4[r];
        float silu = pg / (1.f + __expf(-pg));
        o4[r] = (bf16)(silu * o);
      }
      *(bf16x4*)(grow + d0) = o4;
    }
  };

  run_strip(15 - pr);    // long strip first
  run_strip(pr);         // short strip re-reads L2-warm K/V
}

// ---------------------------------------------------------------------------
extern "C" void kernel_launch(void* const* d_in, const int* in_sizes, int n_in,
                              void* d_out, int out_size, void* d_ws, size_t ws_size,
                              hipStream_t stream) {
  (void)in_sizes; (void)n_in; (void)out_size; (void)ws_size;
  const float* x      = (const float*)d_in[0];
  const float* w_in   = (const float*)d_in[1];
  const float* w_out  = (const float*)d_in[2];
  const float* lnig   = (const float*)d_in[3];
  const float* lnib   = (const float*)d_in[4];
  const float* lnog   = (const float*)d_in[5];
  const float* lnob   = (const float*)d_in[6];
  const float* slopes = (const float*)d_in[7];
  const float* smf    = (const float*)d_in[8];
  float* out = (float*)d_out;

  char* ws = (char*)d_ws;
  size_t off = 0;
  bf16* hb      = (bf16*)(ws + off); off += (size_t)4096 * 1024 * 2;  // h (bf16)
  bf16* w_in_b  = (bf16*)(ws + off); off += (size_t)8192 * 1024 * 2;
  bf16* w_out_b = (bf16*)(ws + off); off += (size_t)1024 * 2048 * 2;
  bf16* qkvp    = (bf16*)(ws + off); off += (size_t)4096 * 8192 * 2;
  bf16* ksm     = (bf16*)(ws + off); off += (size_t)32 * 2048 * 128 * 2;
  bf16* gated   = (bf16*)(ws + off); off += (size_t)4096 * 2048 * 2;
  float* yb     = (float*)(ws + off); off += (size_t)4096 * 1024 * 4;
  bf16* vt      = (bf16*)yb;  // alias: vt dead before gemm2 writes yb

  cvt_kernel<<<4096, 256, 0, stream>>>(w_in,  w_in_b,  8388608 / 8);
  cvt_kernel<<<1024, 256, 0, stream>>>(w_out, w_out_b, 2097152 / 8);
  ln_kernel<true><<<4096, 256, 0, stream>>>(x, lnig, lnib, hb);
  gemm256<<<512, 512, 0, stream>>>(hb, w_in_b, qkvp, 4096, 8192, 1024, 4, 8, 8);
  prep_kernel<<<dim3(32, 32), 256, 0, stream>>>(qkvp, smf, ksm, vt);
  attn_kernel<<<256, 512, 0, stream>>>(qkvp, ksm, vt, slopes, gated);
  gemm_bt<float><<<256, 256, 0, stream>>>(gated, w_out_b, yb, 4096, 1024, 2048, 1, 8, 4);
  ln_kernel<false><<<4096, 256, 0, stream>>>(yb, lnog, lnob, out);
}